// Round 1
// 5373.673 us; speedup vs baseline: 4.5459x; 4.5459x over previous
//
#include <hip/hip_runtime.h>
#include <hip/hip_bf16.h>
#include <math.h>

typedef __hip_bfloat16 bf16;

__device__ __forceinline__ float b2f(bf16 x){ return __bfloat162float(x); }
__device__ __forceinline__ bf16  f2b(float x){ return __float2bfloat16(x); }

#define NUSERS   10000
#define NPOIS    50000
#define SEQL     100
#define NNODES   60001
#define BATCH    1024
#define NNZG     1920000
#define NNZH     1600000
#define BL       (BATCH*SEQL)          // 102400
#define BLD      (BL*128)              // 13,107,200 elems
#define NND      (NNODES*128)          // 7,680,128
#define CN       (60000*128)           // 7,680,000
#define PD       (NPOIS*128)           // 6,400,000

__device__ __forceinline__ void  stc(bf16* p,  float v){ *p = f2b(v); }
__device__ __forceinline__ void  stc(float* p, float v){ *p = v; }
__device__ __forceinline__ float ldc(const bf16* p){ return b2f(*p); }
__device__ __forceinline__ float ldc(const float* p){ return *p; }

// ---------- zero-fill (16B granules; callers guarantee 16B-aligned, n4*16 bytes) ----------
__global__ __launch_bounds__(256) void k_zero(float* __restrict__ p, int n4){
    int i = blockIdx.x*256 + threadIdx.x;
    if (i < n4) ((float4*)p)[i] = make_float4(0.f,0.f,0.f,0.f);
}

// ---------- init: nodes(bf16)=src, acc(f32)=src ----------
__global__ __launch_bounds__(256) void k_init(bf16* __restrict__ nodes, float* __restrict__ acc,
                                              const float* __restrict__ src, int n){
    int i = blockIdx.x*256 + threadIdx.x;
    if (i >= n) return;
    float v = src[i];
    nodes[i] = f2b(v); acc[i] = v;
}

// ---------- row gather bf16 table -> bf16 dst ----------
__global__ __launch_bounds__(256) void k_gather_b(bf16* __restrict__ dst,
                                                  const bf16* __restrict__ table,
                                                  const int* __restrict__ idx, int rows){
    int gid = blockIdx.x*256 + threadIdx.x;
    if (gid >= rows*128) return;
    int r = gid >> 7, c = gid & 127;
    dst[(size_t)r*128 + c] = table[(size_t)idx[r]*128 + c];
}

// ---------- row gather f32 table -> f32 dst ----------
__global__ __launch_bounds__(256) void k_gather_f(float* __restrict__ dst,
                                                  const float* __restrict__ table,
                                                  const int* __restrict__ idx, int rows){
    int gid = blockIdx.x*256 + threadIdx.x;
    if (gid >= rows*128) return;
    int r = gid >> 7, c = gid & 127;
    dst[(size_t)r*128 + c] = table[(size_t)idx[r]*128 + c];
}

// ---------- geo einsum: geo[b,l,c] = sum_s adj[b,l,s]*seq[b,s,c] ----------
__global__ __launch_bounds__(256) void k_geo(bf16* __restrict__ geo,
                                             const bf16* __restrict__ seq,
                                             const float* __restrict__ adj){
    __shared__ float sq[SEQL*128];
    int b = blockIdx.x, tid = threadIdx.x;
    const bf16* src = seq + (size_t)b*SEQL*128;
    for (int i = tid; i < SEQL*128; i += 256) sq[i] = b2f(src[i]);
    __syncthreads();
    const float* ab = adj + (size_t)b*SEQL*SEQL;
    for (int o = tid; o < SEQL*128; o += 256){
        int l = o >> 7, c = o & 127;
        const float* arow = ab + l*SEQL;
        float sum = 0.f;
        for (int s = 0; s < SEQL; s++) sum += arow[s] * sq[s*128 + c];
        geo[(size_t)b*SEQL*128 + o] = f2b(sum);
    }
}

// ---------- tot = seq + geo + pos_local[l+1] ----------
__global__ __launch_bounds__(256) void k_tot(bf16* __restrict__ tot,
                                             const bf16* __restrict__ seq,
                                             const bf16* __restrict__ geo,
                                             const float* __restrict__ posl, int n){
    int i = blockIdx.x*256 + threadIdx.x;
    if (i >= n) return;
    int c = i & 127, bl = i >> 7, l = bl % SEQL;
    tot[i] = f2b(b2f(seq[i]) + b2f(geo[i]) + posl[(l+1)*128 + c]);
}

// ---------- naive in-place-safe GEMM with fused epilogue ----------
// act: 0=none 1=relu 2=tanh 3=sigmoid
// addmode: 0=none
//          1: v += add1[((m%SEQL)+1)*masks[m]*128 + n]   (posW for nh1)
//          2: v += add1[(m/SEQL)*128 + n]                (hproj for nh2)
template<typename TA, typename TC>
__global__ __launch_bounds__(256) void k_ngemm(const TA* __restrict__ A,
                                               const float* __restrict__ W, int wstride, int woff,
                                               const float* __restrict__ bias, int boff,
                                               TC* __restrict__ C, int act,
                                               const float* __restrict__ add1, int addmode,
                                               const int* __restrict__ masks){
    __shared__ float Al[8*130];
    __shared__ float Wl[64*130];
    int tid = threadIdx.x;
    int m0 = blockIdx.x * 8;
    #pragma unroll
    for (int i = 0; i < 4; i++){
        int idx = tid + i*256;            // [0,1024)
        int r = idx >> 7, k = idx & 127;
        Al[r*130 + k] = ldc(&A[(size_t)(m0+r)*128 + k]);
    }
    int n = tid & 127, rb = tid >> 7;     // rb in {0,1}
    float acc[4] = {0.f,0.f,0.f,0.f};
    for (int kp = 0; kp < 128; kp += 64){
        __syncthreads();
        #pragma unroll
        for (int i = 0; i < 32; i++){
            int idx = tid + i*256;        // [0,8192)
            int nn = idx >> 6, kk = idx & 63;
            Wl[kk*130 + nn] = W[(size_t)nn*wstride + woff + kp + kk];
        }
        __syncthreads();
        #pragma unroll
        for (int rr = 0; rr < 4; rr++){
            int r = rb + rr*2;
            float s = 0.f;
            for (int kk = 0; kk < 64; kk++)
                s += Al[r*130 + kp + kk] * Wl[kk*130 + n];
            acc[rr] += s;
        }
    }
    #pragma unroll
    for (int rr = 0; rr < 4; rr++){
        int m = m0 + rb + rr*2;
        float v = acc[rr];
        if (bias) v += bias[boff + n];
        if (addmode == 1){
            int l = m % SEQL;
            int p = (l+1) * masks[m];
            v += add1[p*128 + n];
        } else if (addmode == 2){
            v += add1[(m/SEQL)*128 + n];
        }
        if (act == 1) v = fmaxf(v, 0.f);
        else if (act == 2) v = tanhf(v);
        else if (act == 3) v = 1.f/(1.f+__expf(-v));
        stc(&C[(size_t)m*128 + n], v);
    }
}

// ---------- per-(b,h) attention: softmax(QK^T/4)V; O may alias Q's plane ----------
__global__ __launch_bounds__(256) void k_attn(bf16* __restrict__ o,
                                              const bf16* __restrict__ Qq,
                                              const bf16* __restrict__ Qk,
                                              const bf16* __restrict__ Qv){
    __shared__ float q[SEQL*17], k[SEQL*17], v[SEQL*17], s[SEQL*101];
    int b = blockIdx.x >> 3, h = blockIdx.x & 7, tid = threadIdx.x;
    size_t base = (size_t)b*SEQL*128 + h*16;
    for (int t = tid; t < SEQL*16; t += 256){
        int l = t >> 4, j = t & 15;
        size_t off = base + (size_t)l*128 + j;
        q[l*17+j] = b2f(Qq[off]);
        k[l*17+j] = b2f(Qk[off]);
        v[l*17+j] = b2f(Qv[off]);
    }
    __syncthreads();
    for (int t = tid; t < SEQL*SEQL; t += 256){
        int i = t / SEQL, j = t % SEQL;
        float sum = 0.f;
        #pragma unroll
        for (int u = 0; u < 16; u++) sum += q[i*17+u]*k[j*17+u];
        s[i*101+j] = sum * 0.25f;
    }
    __syncthreads();
    if (tid < SEQL){
        float m = -1e30f;
        for (int j=0;j<SEQL;j++) m = fmaxf(m, s[tid*101+j]);
        float sum = 0.f;
        for (int j=0;j<SEQL;j++){ float e = __expf(s[tid*101+j]-m); s[tid*101+j]=e; sum+=e; }
        float inv = 1.f/sum;
        for (int j=0;j<SEQL;j++) s[tid*101+j] *= inv;
    }
    __syncthreads();
    for (int t = tid; t < SEQL*16; t += 256){
        int i = t >> 4, u = t & 15;
        float sum = 0.f;
        for (int j = 0; j < SEQL; j++) sum += s[i*101+j]*v[j*17+u];
        o[base + (size_t)i*128 + u] = f2b(sum);
    }
}

// ---------- users = mean_l(o2) -> nodes[uidx[b]] ----------
__global__ __launch_bounds__(128) void k_mean_users(bf16* __restrict__ nodes,
                                                    const bf16* __restrict__ o,
                                                    const int* __restrict__ uidx){
    int b = blockIdx.x, c = threadIdx.x;
    const bf16* p = o + (size_t)b*SEQL*128 + c;
    float sum = 0.f;
    for (int l = 0; l < SEQL; l++) sum += b2f(p[l*128]);
    nodes[(size_t)uidx[b]*128 + c] = f2b(sum * (1.f/(float)SEQL));
}

// ================= CSR build + row-wave SpMM (replaces atomic COO SpMM) =================

// histogram: cnt[rows[e]]++
__global__ __launch_bounds__(256) void k_hist(int* __restrict__ cnt,
                                              const int* __restrict__ rows, int nnz){
    int e = blockIdx.x*256 + threadIdx.x;
    if (e < nnz) atomicAdd(&cnt[rows[e]], 1);
}

// single-block exclusive scan: rowptr[0..nrows] from cnt; cnt rewritten to start offsets
__global__ __launch_bounds__(1024) void k_scan(int* __restrict__ cnt,
                                               int* __restrict__ rowptr, int nrows){
    __shared__ int part[1024];
    int tid = threadIdx.x;
    int chunk = (nrows + 1023) >> 10;
    int s = tid*chunk, e = min(s+chunk, nrows);
    int sum = 0;
    for (int i = s; i < e; i++) sum += cnt[i];
    part[tid] = sum;
    __syncthreads();
    for (int off = 1; off < 1024; off <<= 1){
        int add = (tid >= off) ? part[tid-off] : 0;
        __syncthreads();
        part[tid] += add;
        __syncthreads();
    }
    int run = part[tid] - sum;      // exclusive prefix of this thread's chunk
    for (int i = s; i < e; i++){
        int c = cnt[i];
        rowptr[i] = run;
        cnt[i]    = run;            // becomes the scatter cursor
        run += c;
    }
    if (tid == 0) rowptr[nrows] = part[1023];
}

// scatter edges into CSR order: cv[pos] = (col, val-bits)
__global__ __launch_bounds__(256) void k_scatter(int2* __restrict__ cv,
                                                 int* __restrict__ cur,
                                                 const int* __restrict__ rows,
                                                 const int* __restrict__ cols,
                                                 const float* __restrict__ vals, int nnz){
    int e = blockIdx.x*256 + threadIdx.x;
    if (e >= nnz) return;
    int p = atomicAdd(&cur[rows[e]], 1);
    cv[p] = make_int2(cols[e], __float_as_int(vals[e]));
}

// one wave per row; lane owns 2 columns; f32 register accumulate; no atomics.
__global__ __launch_bounds__(256) void k_spmm_csr(float* __restrict__ y,
                                                  const int* __restrict__ rowptr,
                                                  const int2* __restrict__ cv,
                                                  const bf16* __restrict__ x, int nrows){
    int row = blockIdx.x*4 + (threadIdx.x >> 6);
    if (row >= nrows) return;
    int lane = threadIdx.x & 63;
    int s = rowptr[row], e = rowptr[row+1];
    float a0 = 0.f, a1 = 0.f;
    for (int i = s; i < e; i++){
        int2 p = cv[i];
        float v = __int_as_float(p.y);
        unsigned u = *(const unsigned*)(x + (size_t)p.x*128 + lane*2);
        a0 += v * __uint_as_float((u & 0xffffu) << 16);
        a1 += v * __uint_as_float(u & 0xffff0000u);
    }
    float* yp = y + (size_t)row*128 + lane*2;
    *(float2*)yp = make_float2(a0, a1);
}

// ---------- nodes(bf16)[:60000] = Cbuf; acc(f32) += Cbuf ----------
__global__ __launch_bounds__(256) void k_commit(bf16* __restrict__ nodes, float* __restrict__ acc,
                                                const float* __restrict__ Cb, int n){
    int i = blockIdx.x*256 + threadIdx.x;
    if (i >= n) return;
    float v = Cb[i];
    nodes[i] = f2b(v);
    acc[i] += v;
}

__global__ __launch_bounds__(256) void k_scale(float* __restrict__ a, int n){
    int i = blockIdx.x*256 + threadIdx.x;
    if (i < n) a[i] *= (1.f/3.f);
}

// ---------- global branch init ----------
__global__ __launch_bounds__(256) void k_initg(bf16* __restrict__ xg, float* __restrict__ accg,
                                               const float* __restrict__ ne, int n){
    int i = blockIdx.x*256 + threadIdx.x;
    if (i >= n) return;
    float v = ne[(size_t)NUSERS*128 + i];
    xg[i] = f2b(v); accg[i] = v;
}

__global__ __launch_bounds__(256) void k_commit2(bf16* __restrict__ xg, float* __restrict__ accg,
                                                 const float* __restrict__ tmp, int n){
    int i = blockIdx.x*256 + threadIdx.x;
    if (i >= n) return;
    float v = tmp[i];
    xg[i] = f2b(v);
    accg[i] += v;
}

// ---------- fusion: acc_poi += accg/3; emit pois output (f32!) ----------
__global__ __launch_bounds__(256) void k_fusion(float* __restrict__ accP,
                                                const float* __restrict__ accg,
                                                float* __restrict__ outp, int n){
    int i = blockIdx.x*256 + threadIdx.x;
    if (i >= n) return;
    float v = accP[i] + accg[i]*(1.f/3.f);
    accP[i] = v;
    outp[i] = v;
}

// ================= HEAD =================

__global__ __launch_bounds__(128) void k_hs(float* __restrict__ hs, const float* __restrict__ sh,
                                            const float* __restrict__ lens){
    int b = blockIdx.x, c = threadIdx.x;
    const float* p = sh + (size_t)b*SEQL*128 + c;
    float sum = 0.f;
    for (int l = 0; l < SEQL; l++) sum += p[l*128];
    hs[b*128 + c] = sum / lens[b];
}

__global__ __launch_bounds__(128) void k_posw(float* __restrict__ posW,
                                              const float* __restrict__ pg,
                                              const float* __restrict__ w1w){
    __shared__ float sm[128];
    int p = blockIdx.x, n = threadIdx.x;
    sm[n] = pg[p*128 + n];
    __syncthreads();
    const float* wr = w1w + (size_t)n*256;
    float s = 0.f;
    for (int k = 0; k < 128; k++) s += sm[k]*wr[k];
    posW[p*128 + n] = s;
}

__global__ __launch_bounds__(128) void k_beta(float* __restrict__ beta,
                                              const bf16* __restrict__ nh,
                                              const float* __restrict__ w2){
    __shared__ float red[128];
    int m = blockIdx.x, c = threadIdx.x;
    red[c] = b2f(nh[(size_t)m*128 + c]) * w2[c];
    __syncthreads();
    for (int s = 64; s > 0; s >>= 1){
        if (c < s) red[c] += red[c+s];
        __syncthreads();
    }
    if (c == 0) beta[m] = red[0];
}

__global__ __launch_bounds__(128) void k_final(float* __restrict__ out,
                                               const float* __restrict__ beta,
                                               const float* __restrict__ seqh,
                                               const float* __restrict__ acc,
                                               const int* __restrict__ uidx){
    int b = blockIdx.x, c = threadIdx.x;
    const float* sh = seqh + (size_t)b*SEQL*128 + c;
    const float* bp = beta + b*SEQL;
    float sel = 0.f;
    for (int l = 0; l < SEQL; l++) sel += bp[l]*sh[l*128];
    out[b*128 + c] = sel + acc[(size_t)uidx[b]*128 + c];
}

extern "C" void kernel_launch(void* const* d_in, const int* in_sizes, int n_in,
                              void* d_out, int out_size, void* d_ws, size_t ws_size,
                              hipStream_t stream){
    const float* nodes_emb     = (const float*)d_in[0];
    const float* pos_emb_local = (const float*)d_in[1];
    const float* fc_geo_w      = (const float*)d_in[2];
    const float* fc_geo_b      = (const float*)d_in[3];
    const float* in_proj_w     = (const float*)d_in[4];
    const float* in_proj_b     = (const float*)d_in[5];
    const float* out_proj_w    = (const float*)d_in[6];
    const float* out_proj_b    = (const float*)d_in[7];
    const float* pos_emb_glob  = (const float*)d_in[8];
    const float* w1_w          = (const float*)d_in[9];
    const float* w1_b          = (const float*)d_in[10];
    const float* w_2           = (const float*)d_in[11];
    const float* glu1_w        = (const float*)d_in[12];
    const float* glu1_b        = (const float*)d_in[13];
    const float* glu2_w        = (const float*)d_in[14];
    const int*   G_rows        = (const int*)d_in[15];
    const int*   G_cols        = (const int*)d_in[16];
    const float* G_vals        = (const float*)d_in[17];
    const int*   HG_rows       = (const int*)d_in[18];
    const int*   HG_cols       = (const int*)d_in[19];
    const float* HG_vals       = (const float*)d_in[20];
    const int*   seqs          = (const int*)d_in[21];
    const int*   masks         = (const int*)d_in[22];
    const float* adjs          = (const float*)d_in[23];
    const int*   uidx          = (const int*)d_in[24];
    const float* lens          = (const float*)d_in[25];
    const int*   rev_seqs      = (const int*)d_in[26];
    float* out = (float*)d_out;   // OUTPUT IS FLOAT32

    // ---- workspace layout; max offset used = 124,723,968 B (same footprint as before) ----
    char* base = (char*)d_ws;
    bf16*  nodes = (bf16*)base;                               // [0, 15,360,256)
    float* acc   = (float*)(base + 15360256);                 // [.., 46,080,768)
    char*  R     = base + 15360256 + 30720512;                // [46,080,768, 124,723,968)
    // layer-phase aliases inside R:
    bf16* P1 = (bf16*)R;          // BLD bf16
    bf16* P2 = P1 + BLD;
    bf16* P3 = P2 + BLD;
    // spmm-window aliases (P1/P2/P3 dead):
    float* Cbuf = (float*)R;                         // CN f32: [R, R+30,720,000)
    int2*  Gcv  = (int2*)(R + 30720000);             // NNZG*8 = 15,360,000 -> ends 46,080,000
    int*   Gptr = (int*)(R + 46080000);              // 60001*4 -> ends 46,320,004
    int*   Gcur = (int*)(R + 46320016);              // 60000*4 -> ends 46,560,016 (16B aligned)
    // global-phase aliases:
    bf16*  xg   = (bf16*)R;                          // PD bf16
    float* gtmp = (float*)(R + 12800000);            // PD f32
    float* accg = (float*)(R + 12800000 + 25600000); // PD f32 -> ends 64,000,000
    int2*  Hcv  = (int2*)(R + 64000000);             // NNZH*8 = 12,800,000 -> ends 76,800,000
    int*   Hptr = (int*)(R + 76800000);              // 50001*4 -> ends 77,000,004
    int*   Hcur = (int*)(R + 77000016);              // 50000*4 -> ends 77,200,016 (16B aligned)
    // head-phase aliases:
    float* H1f  = (float*)R;                         // BLD f32
    bf16*  nh   = (bf16*)(R + 52428800);             // BLD bf16 -> ends 78,643,200
    float* hs    = (float*)base;                     // small bufs in dead nodes region
    float* hproj = (float*)(base + 524288);
    float* posW  = (float*)(base + 1048576);
    float* betaB = (float*)(base + 1100288);

    auto gemm = [&](const bf16* A, const float* W, int wstride, int woff,
                    const float* bias, int boff, bf16* Cp, int act){
        k_ngemm<bf16,bf16><<<dim3(BL/8), dim3(256), 0, stream>>>(
            A, W, wstride, woff, bias, boff, Cp, act, nullptr, 0, nullptr);
    };

    // init: nodes (bf16) = nodes_emb, acc (f32) = nodes_emb
    k_init<<<dim3((NND+255)/256), dim3(256), 0, stream>>>(nodes, acc, nodes_emb, NND);

    for (int layer = 0; layer < 2; layer++){
        k_gather_b<<<dim3((BL*128+255)/256), dim3(256), 0, stream>>>(P1, nodes, seqs, BL);
        k_geo<<<dim3(BATCH), dim3(256), 0, stream>>>(P2, P1, adjs);
        gemm(P2, fc_geo_w, 128, 0, fc_geo_b, 0, P2, 1);   // relu, in-place (row-owned)
        k_tot<<<dim3((BLD+255)/256), dim3(256), 0, stream>>>(P3, P1, P2, pos_emb_local, BLD);
        gemm(P3, in_proj_w, 128, 0,       in_proj_b, 0,   P1, 0); // Q
        gemm(P3, in_proj_w, 128, 128*128, in_proj_b, 128, P2, 0); // K
        gemm(P3, in_proj_w, 128, 256*128, in_proj_b, 256, P3, 0); // V in-place
        k_attn<<<dim3(BATCH*8), dim3(256), 0, stream>>>(P1, P1, P2, P3);  // O over Q
        gemm(P1, out_proj_w, 128, 0, out_proj_b, 0, P2, 0);
        k_mean_users<<<dim3(BATCH), dim3(128), 0, stream>>>(nodes, P2, uidx);
        // ---- build G CSR (scratch lives in dead P2/P3 space; rebuilt each layer) ----
        k_zero<<<dim3((15000+255)/256), dim3(256), 0, stream>>>((float*)Gcur, 15000); // 60000 ints
        k_hist<<<dim3(NNZG/256), dim3(256), 0, stream>>>(Gcur, G_rows, NNZG);
        k_scan<<<dim3(1), dim3(1024), 0, stream>>>(Gcur, Gptr, 60000);
        k_scatter<<<dim3(NNZG/256), dim3(256), 0, stream>>>(Gcv, Gcur, G_rows, G_cols, G_vals, NNZG);
        // ---- row-wave SpMM, no atomics, writes every row (no zero of Cbuf needed) ----
        k_spmm_csr<<<dim3(60000/4), dim3(256), 0, stream>>>(Cbuf, Gptr, Gcv, nodes, 60000);
        k_commit<<<dim3((CN+255)/256), dim3(256), 0, stream>>>(nodes, acc, Cbuf, CN);
    }
    // local = acc/3
    k_scale<<<dim3((NND+255)/256), dim3(256), 0, stream>>>(acc, NND);

    // global hypergraph branch
    k_initg<<<dim3((PD+255)/256), dim3(256), 0, stream>>>(xg, accg, nodes_emb, PD);
    // build HG CSR once (tail of R, dead during global phase)
    k_zero<<<dim3((12500+255)/256), dim3(256), 0, stream>>>((float*)Hcur, 12500); // 50000 ints
    k_hist<<<dim3(NNZH/256), dim3(256), 0, stream>>>(Hcur, HG_rows, NNZH);
    k_scan<<<dim3(1), dim3(1024), 0, stream>>>(Hcur, Hptr, 50000);
    k_scatter<<<dim3(NNZH/256), dim3(256), 0, stream>>>(Hcv, Hcur, HG_rows, HG_cols, HG_vals, NNZH);
    for (int it = 0; it < 2; it++){
        k_spmm_csr<<<dim3(50000/4), dim3(256), 0, stream>>>(gtmp, Hptr, Hcv, xg, 50000);
        k_commit2<<<dim3((PD+255)/256), dim3(256), 0, stream>>>(xg, accg, gtmp, PD);
    }
    // fusion: pois rows of acc += accg/3, emit pois output (f32, offset in f32 elems)
    k_fusion<<<dim3((PD+255)/256), dim3(256), 0, stream>>>(acc + (size_t)NUSERS*128, accg, out + BATCH*128, PD);

    // ===== head (f32 path) =====
    k_gather_f<<<dim3((BL*128+255)/256), dim3(256), 0, stream>>>(H1f, acc, rev_seqs, BL);
    k_hs<<<dim3(BATCH), dim3(128), 0, stream>>>(hs, H1f, lens);
    // hproj = hs @ glu2_w^T  (tiled GEMM, coalesced W)
    k_ngemm<float,float><<<dim3(BATCH/8), dim3(256), 0, stream>>>(
        hs, glu2_w, 128, 0, nullptr, 0, hproj, 0, nullptr, 0, nullptr);
    k_posw<<<dim3(SEQL+1), dim3(128), 0, stream>>>(posW, pos_emb_glob, w1_w);
    // nh1 = tanh(H1f @ w1_w[:,128:]^T + posW[pidx] + w1_b)
    k_ngemm<float,bf16><<<dim3(BL/8), dim3(256), 0, stream>>>(
        H1f, w1_w, 256, 128, w1_b, 0, nh, 2, posW, 1, masks);
    // nh2 = sigmoid(nh @ glu1_w^T + glu1_b + hproj[b])  (in-place, row-owned)
    k_ngemm<bf16,bf16><<<dim3(BL/8), dim3(256), 0, stream>>>(
        nh, glu1_w, 128, 0, glu1_b, 0, nh, 3, hproj, 2, nullptr);
    k_beta<<<dim3(BL), dim3(128), 0, stream>>>(betaB, nh, w_2);
    k_final<<<dim3(BATCH), dim3(128), 0, stream>>>(out, betaB, H1f, acc, uidx);
}

// Round 3
// 3964.937 us; speedup vs baseline: 6.1610x; 1.3553x over previous
//
#include <hip/hip_runtime.h>
#include <hip/hip_bf16.h>
#include <math.h>

typedef __hip_bfloat16 bf16;

__device__ __forceinline__ float b2f(bf16 x){ return __bfloat162float(x); }
__device__ __forceinline__ bf16  f2b(float x){ return __float2bfloat16(x); }

// raw-bits bf16 helpers (RNE, finite inputs)
__device__ __forceinline__ short f2bs(float f){
    unsigned u = __float_as_uint(f);
    u += 0x7fffu + ((u >> 16) & 1u);
    return (short)(u >> 16);
}
__device__ __forceinline__ float bs2f(short s){
    return __uint_as_float(((unsigned)(unsigned short)s) << 16);
}

#define NUSERS   10000
#define NPOIS    50000
#define SEQL     100
#define NNODES   60001
#define BATCH    1024
#define NNZG     1920000
#define NNZH     1600000
#define BL       (BATCH*SEQL)          // 102400
#define BLD      (BL*128)              // 13,107,200 elems
#define NND      (NNODES*128)          // 7,680,128
#define CN       (60000*128)           // 7,680,000
#define PD       (NPOIS*128)           // 6,400,000

__device__ __forceinline__ void  stc(bf16* p,  float v){ *p = f2b(v); }
__device__ __forceinline__ void  stc(float* p, float v){ *p = v; }

typedef __attribute__((ext_vector_type(8))) short s16x8;
typedef __attribute__((ext_vector_type(4))) float f32x4;

// ---------- zero-fill (16B granules) ----------
__global__ __launch_bounds__(256) void k_zero(float* __restrict__ p, int n4){
    int i = blockIdx.x*256 + threadIdx.x;
    if (i < n4) ((float4*)p)[i] = make_float4(0.f,0.f,0.f,0.f);
}

// ---------- init: nodes(bf16)=src, acc(f32)=src ----------
__global__ __launch_bounds__(256) void k_init(bf16* __restrict__ nodes, float* __restrict__ acc,
                                              const float* __restrict__ src, int n){
    int i = blockIdx.x*256 + threadIdx.x;
    if (i >= n) return;
    float v = src[i];
    nodes[i] = f2b(v); acc[i] = v;
}

// ---------- row gather bf16 table -> bf16 dst ----------
__global__ __launch_bounds__(256) void k_gather_b(bf16* __restrict__ dst,
                                                  const bf16* __restrict__ table,
                                                  const int* __restrict__ idx, int rows){
    int gid = blockIdx.x*256 + threadIdx.x;
    if (gid >= rows*128) return;
    int r = gid >> 7, c = gid & 127;
    dst[(size_t)r*128 + c] = table[(size_t)idx[r]*128 + c];
}

// ---------- row gather f32 table -> f32 dst ----------
__global__ __launch_bounds__(256) void k_gather_f(float* __restrict__ dst,
                                                  const float* __restrict__ table,
                                                  const int* __restrict__ idx, int rows){
    int gid = blockIdx.x*256 + threadIdx.x;
    if (gid >= rows*128) return;
    int r = gid >> 7, c = gid & 127;
    dst[(size_t)r*128 + c] = table[(size_t)idx[r]*128 + c];
}

// ---------- geo einsum: geo[b,l,c] = sum_s adj[b,l,s]*seq[b,s,c] ----------
__global__ __launch_bounds__(256) void k_geo(bf16* __restrict__ geo,
                                             const bf16* __restrict__ seq,
                                             const float* __restrict__ adj){
    __shared__ float sq[SEQL*128];
    int b = blockIdx.x, tid = threadIdx.x;
    const bf16* src = seq + (size_t)b*SEQL*128;
    for (int i = tid; i < SEQL*128; i += 256) sq[i] = b2f(src[i]);
    __syncthreads();
    const float* ab = adj + (size_t)b*SEQL*SEQL;
    for (int o = tid; o < SEQL*128; o += 256){
        int l = o >> 7, c = o & 127;
        const float* arow = ab + l*SEQL;
        float sum = 0.f;
        for (int s = 0; s < SEQL; s++) sum += arow[s] * sq[s*128 + c];
        geo[(size_t)b*SEQL*128 + o] = f2b(sum);
    }
}

// ---------- tot = seq + geo + pos_local[l+1] ----------
__global__ __launch_bounds__(256) void k_tot(bf16* __restrict__ tot,
                                             const bf16* __restrict__ seq,
                                             const bf16* __restrict__ geo,
                                             const float* __restrict__ posl, int n){
    int i = blockIdx.x*256 + threadIdx.x;
    if (i >= n) return;
    int c = i & 127, bl = i >> 7, l = bl % SEQL;
    tot[i] = f2b(b2f(seq[i]) + b2f(geo[i]) + posl[(l+1)*128 + c]);
}

// ================= MFMA GEMM =================
// C[M,128] = epilogue( A[M,128] @ W[n, wstride; +woff]^T )
// W is f32 in HBM; split in-register into bf16 hi+lo (W-precision ~2^-17).
// TA = bf16  -> 2 MFMA terms: A@Whi + A@Wlo
// TA = float -> 3 MFMA terms: Ahi@Whi + Ahi@Wlo + Alo@Whi
// act: 0=none 1=relu 2=tanh 3=sigmoid
// addmode: 1: v += add1[((m%SEQL)+1)*masks[m]*128 + n]  (posW for nh1)
//          2: v += add1[(m/SEQL)*128 + n]               (hproj for nh2)
// Requires M % 128 == 0; grid = M/128.
// IN-PLACE SAFE: per 16-row stripe, a __syncthreads() separates all waves'
// A-fragment loads from the stores of that stripe (stripe it+1 loads touch
// disjoint rows, so one barrier per stripe suffices).
template<typename TA, typename TC>
__global__ __launch_bounds__(256) void k_mgemm(const TA* __restrict__ A,
                                               const float* __restrict__ W, int wstride, int woff,
                                               const float* __restrict__ bias, int boff,
                                               TC* __restrict__ C, int act,
                                               const float* __restrict__ add1, int addmode,
                                               const int* __restrict__ masks){
    constexpr bool A_BF = (sizeof(TA) == 2);
    int tid  = threadIdx.x;
    int wv   = tid >> 6;          // wave 0..3 -> col slice
    int lane = tid & 63;
    int lr   = lane & 15;         // A-row / B-col / C-col within tile
    int lk   = lane >> 4;         // k-group 0..3
    int n0   = wv * 32;

    // ---- load + split W fragments once per block; held in VGPRs ----
    // B[k][n] = W[n][k]; lane frag: col = n0+t*16+lr, k = ks*32 + lk*8 + j
    s16x8 wh[2][4], wl[2][4];
    #pragma unroll
    for (int t = 0; t < 2; t++){
        #pragma unroll
        for (int ks = 0; ks < 4; ks++){
            const float* wp = W + (size_t)(n0 + t*16 + lr)*wstride + woff + ks*32 + lk*8;
            float4 w0 = *(const float4*)(wp);
            float4 w1 = *(const float4*)(wp + 4);
            float wf[8] = {w0.x,w0.y,w0.z,w0.w,w1.x,w1.y,w1.z,w1.w};
            s16x8 h, l;
            #pragma unroll
            for (int j = 0; j < 8; j++){
                short hb = f2bs(wf[j]);
                h[j] = hb;
                l[j] = f2bs(wf[j] - bs2f(hb));
            }
            wh[t][ks] = h; wl[t][ks] = l;
        }
    }

    size_t mblk = (size_t)blockIdx.x * 128;
    for (int it = 0; it < 8; it++){
        size_t m0 = mblk + (size_t)it*16;
        s16x8 ah[4], al[4];
        #pragma unroll
        for (int ks = 0; ks < 4; ks++){
            if constexpr (A_BF){
                ah[ks] = *(const s16x8*)((const short*)A + (m0 + lr)*128 + ks*32 + lk*8);
            } else {
                const float* ap = (const float*)A + (m0 + lr)*128 + ks*32 + lk*8;
                float4 a0 = *(const float4*)(ap);
                float4 a1 = *(const float4*)(ap + 4);
                float av[8] = {a0.x,a0.y,a0.z,a0.w,a1.x,a1.y,a1.z,a1.w};
                s16x8 h, l;
                #pragma unroll
                for (int j = 0; j < 8; j++){
                    short hb = f2bs(av[j]);
                    h[j] = hb;
                    l[j] = f2bs(av[j] - bs2f(hb));
                }
                ah[ks] = h; al[ks] = l;
            }
        }
        // all waves must finish reading this stripe of A before any wave
        // overwrites it (in-place calls: fc_geo, V, nh2).
        __syncthreads();
        f32x4 c0 = {0.f,0.f,0.f,0.f}, c1 = {0.f,0.f,0.f,0.f};
        #pragma unroll
        for (int ks = 0; ks < 4; ks++){
            c0 = __builtin_amdgcn_mfma_f32_16x16x32_bf16(ah[ks], wh[0][ks], c0, 0, 0, 0);
            c0 = __builtin_amdgcn_mfma_f32_16x16x32_bf16(ah[ks], wl[0][ks], c0, 0, 0, 0);
            c1 = __builtin_amdgcn_mfma_f32_16x16x32_bf16(ah[ks], wh[1][ks], c1, 0, 0, 0);
            c1 = __builtin_amdgcn_mfma_f32_16x16x32_bf16(ah[ks], wl[1][ks], c1, 0, 0, 0);
            if constexpr (!A_BF){
                c0 = __builtin_amdgcn_mfma_f32_16x16x32_bf16(al[ks], wh[0][ks], c0, 0, 0, 0);
                c1 = __builtin_amdgcn_mfma_f32_16x16x32_bf16(al[ks], wh[1][ks], c1, 0, 0, 0);
            }
        }
        // epilogue + store: C row = lk*4 + r4, col = n0 + t*16 + lr  (m89 layout)
        #pragma unroll
        for (int t = 0; t < 2; t++){
            f32x4 cc = t ? c1 : c0;
            int c = n0 + t*16 + lr;
            float bv = bias ? bias[boff + c] : 0.f;
            #pragma unroll
            for (int r4 = 0; r4 < 4; r4++){
                int m = (int)m0 + lk*4 + r4;
                float v = cc[r4] + bv;
                if (addmode == 1){
                    int l = m % SEQL;
                    int p = (l+1) * masks[m];
                    v += add1[p*128 + c];
                } else if (addmode == 2){
                    v += add1[(m/SEQL)*128 + c];
                }
                if (act == 1) v = fmaxf(v, 0.f);
                else if (act == 2) v = tanhf(v);
                else if (act == 3) v = 1.f/(1.f+__expf(-v));
                stc(&C[(size_t)m*128 + c], v);
            }
        }
    }
}

// ---------- per-(b,h) attention: softmax(QK^T/4)V; O may alias Q's plane ----------
__global__ __launch_bounds__(256) void k_attn(bf16* __restrict__ o,
                                              const bf16* __restrict__ Qq,
                                              const bf16* __restrict__ Qk,
                                              const bf16* __restrict__ Qv){
    __shared__ float q[SEQL*17], k[SEQL*17], v[SEQL*17], s[SEQL*101];
    int b = blockIdx.x >> 3, h = blockIdx.x & 7, tid = threadIdx.x;
    size_t base = (size_t)b*SEQL*128 + h*16;
    for (int t = tid; t < SEQL*16; t += 256){
        int l = t >> 4, j = t & 15;
        size_t off = base + (size_t)l*128 + j;
        q[l*17+j] = b2f(Qq[off]);
        k[l*17+j] = b2f(Qk[off]);
        v[l*17+j] = b2f(Qv[off]);
    }
    __syncthreads();
    for (int t = tid; t < SEQL*SEQL; t += 256){
        int i = t / SEQL, j = t % SEQL;
        float sum = 0.f;
        #pragma unroll
        for (int u = 0; u < 16; u++) sum += q[i*17+u]*k[j*17+u];
        s[i*101+j] = sum * 0.25f;
    }
    __syncthreads();
    if (tid < SEQL){
        float m = -1e30f;
        for (int j=0;j<SEQL;j++) m = fmaxf(m, s[tid*101+j]);
        float sum = 0.f;
        for (int j=0;j<SEQL;j++){ float e = __expf(s[tid*101+j]-m); s[tid*101+j]=e; sum+=e; }
        float inv = 1.f/sum;
        for (int j=0;j<SEQL;j++) s[tid*101+j] *= inv;
    }
    __syncthreads();
    for (int t = tid; t < SEQL*16; t += 256){
        int i = t >> 4, u = t & 15;
        float sum = 0.f;
        for (int j = 0; j < SEQL; j++) sum += s[i*101+j]*v[j*17+u];
        o[base + (size_t)i*128 + u] = f2b(sum);
    }
}

// ---------- users = mean_l(o2) -> nodes[uidx[b]] ----------
__global__ __launch_bounds__(128) void k_mean_users(bf16* __restrict__ nodes,
                                                    const bf16* __restrict__ o,
                                                    const int* __restrict__ uidx){
    int b = blockIdx.x, c = threadIdx.x;
    const bf16* p = o + (size_t)b*SEQL*128 + c;
    float sum = 0.f;
    for (int l = 0; l < SEQL; l++) sum += b2f(p[l*128]);
    nodes[(size_t)uidx[b]*128 + c] = f2b(sum * (1.f/(float)SEQL));
}

// ================= CSR build + row-wave SpMM =================

__global__ __launch_bounds__(256) void k_hist(int* __restrict__ cnt,
                                              const int* __restrict__ rows, int nnz){
    int e = blockIdx.x*256 + threadIdx.x;
    if (e < nnz) atomicAdd(&cnt[rows[e]], 1);
}

__global__ __launch_bounds__(1024) void k_scan(int* __restrict__ cnt,
                                               int* __restrict__ rowptr, int nrows){
    __shared__ int part[1024];
    int tid = threadIdx.x;
    int chunk = (nrows + 1023) >> 10;
    int s = tid*chunk, e = min(s+chunk, nrows);
    int sum = 0;
    for (int i = s; i < e; i++) sum += cnt[i];
    part[tid] = sum;
    __syncthreads();
    for (int off = 1; off < 1024; off <<= 1){
        int add = (tid >= off) ? part[tid-off] : 0;
        __syncthreads();
        part[tid] += add;
        __syncthreads();
    }
    int run = part[tid] - sum;
    for (int i = s; i < e; i++){
        int c = cnt[i];
        rowptr[i] = run;
        cnt[i]    = run;
        run += c;
    }
    if (tid == 0) rowptr[nrows] = part[1023];
}

__global__ __launch_bounds__(256) void k_scatter(int2* __restrict__ cv,
                                                 int* __restrict__ cur,
                                                 const int* __restrict__ rows,
                                                 const int* __restrict__ cols,
                                                 const float* __restrict__ vals, int nnz){
    int e = blockIdx.x*256 + threadIdx.x;
    if (e >= nnz) return;
    int p = atomicAdd(&cur[rows[e]], 1);
    cv[p] = make_int2(cols[e], __float_as_int(vals[e]));
}

__global__ __launch_bounds__(256) void k_spmm_csr(float* __restrict__ y,
                                                  const int* __restrict__ rowptr,
                                                  const int2* __restrict__ cv,
                                                  const bf16* __restrict__ x, int nrows){
    int row = blockIdx.x*4 + (threadIdx.x >> 6);
    if (row >= nrows) return;
    int lane = threadIdx.x & 63;
    int s = rowptr[row], e = rowptr[row+1];
    float a0 = 0.f, a1 = 0.f;
    for (int i = s; i < e; i++){
        int2 p = cv[i];
        float v = __int_as_float(p.y);
        unsigned u = *(const unsigned*)(x + (size_t)p.x*128 + lane*2);
        a0 += v * __uint_as_float((u & 0xffffu) << 16);
        a1 += v * __uint_as_float(u & 0xffff0000u);
    }
    float* yp = y + (size_t)row*128 + lane*2;
    *(float2*)yp = make_float2(a0, a1);
}

// ---------- nodes(bf16)[:60000] = Cbuf; acc(f32) += Cbuf ----------
__global__ __launch_bounds__(256) void k_commit(bf16* __restrict__ nodes, float* __restrict__ acc,
                                                const float* __restrict__ Cb, int n){
    int i = blockIdx.x*256 + threadIdx.x;
    if (i >= n) return;
    float v = Cb[i];
    nodes[i] = f2b(v);
    acc[i] += v;
}

__global__ __launch_bounds__(256) void k_scale(float* __restrict__ a, int n){
    int i = blockIdx.x*256 + threadIdx.x;
    if (i < n) a[i] *= (1.f/3.f);
}

// ---------- global branch init ----------
__global__ __launch_bounds__(256) void k_initg(bf16* __restrict__ xg, float* __restrict__ accg,
                                               const float* __restrict__ ne, int n){
    int i = blockIdx.x*256 + threadIdx.x;
    if (i >= n) return;
    float v = ne[(size_t)NUSERS*128 + i];
    xg[i] = f2b(v); accg[i] = v;
}

__global__ __launch_bounds__(256) void k_commit2(bf16* __restrict__ xg, float* __restrict__ accg,
                                                 const float* __restrict__ tmp, int n){
    int i = blockIdx.x*256 + threadIdx.x;
    if (i >= n) return;
    float v = tmp[i];
    xg[i] = f2b(v);
    accg[i] += v;
}

// ---------- fusion: acc_poi += accg/3; emit pois output (f32!) ----------
__global__ __launch_bounds__(256) void k_fusion(float* __restrict__ accP,
                                                const float* __restrict__ accg,
                                                float* __restrict__ outp, int n){
    int i = blockIdx.x*256 + threadIdx.x;
    if (i >= n) return;
    float v = accP[i] + accg[i]*(1.f/3.f);
    accP[i] = v;
    outp[i] = v;
}

// ================= HEAD =================

__global__ __launch_bounds__(128) void k_hs(float* __restrict__ hs, const float* __restrict__ sh,
                                            const float* __restrict__ lens){
    int b = blockIdx.x, c = threadIdx.x;
    const float* p = sh + (size_t)b*SEQL*128 + c;
    float sum = 0.f;
    for (int l = 0; l < SEQL; l++) sum += p[l*128];
    hs[b*128 + c] = sum / lens[b];
}

__global__ __launch_bounds__(128) void k_posw(float* __restrict__ posW,
                                              const float* __restrict__ pg,
                                              const float* __restrict__ w1w){
    __shared__ float sm[128];
    int p = blockIdx.x, n = threadIdx.x;
    sm[n] = pg[p*128 + n];
    __syncthreads();
    const float* wr = w1w + (size_t)n*256;
    float s = 0.f;
    for (int k = 0; k < 128; k++) s += sm[k]*wr[k];
    posW[p*128 + n] = s;
}

__global__ __launch_bounds__(128) void k_beta(float* __restrict__ beta,
                                              const bf16* __restrict__ nh,
                                              const float* __restrict__ w2){
    __shared__ float red[128];
    int m = blockIdx.x, c = threadIdx.x;
    red[c] = b2f(nh[(size_t)m*128 + c]) * w2[c];
    __syncthreads();
    for (int s = 64; s > 0; s >>= 1){
        if (c < s) red[c] += red[c+s];
        __syncthreads();
    }
    if (c == 0) beta[m] = red[0];
}

__global__ __launch_bounds__(128) void k_final(float* __restrict__ out,
                                               const float* __restrict__ beta,
                                               const float* __restrict__ seqh,
                                               const float* __restrict__ acc,
                                               const int* __restrict__ uidx){
    int b = blockIdx.x, c = threadIdx.x;
    const float* sh = seqh + (size_t)b*SEQL*128 + c;
    const float* bp = beta + b*SEQL;
    float sel = 0.f;
    for (int l = 0; l < SEQL; l++) sel += bp[l]*sh[l*128];
    out[b*128 + c] = sel + acc[(size_t)uidx[b]*128 + c];
}

extern "C" void kernel_launch(void* const* d_in, const int* in_sizes, int n_in,
                              void* d_out, int out_size, void* d_ws, size_t ws_size,
                              hipStream_t stream){
    const float* nodes_emb     = (const float*)d_in[0];
    const float* pos_emb_local = (const float*)d_in[1];
    const float* fc_geo_w      = (const float*)d_in[2];
    const float* fc_geo_b      = (const float*)d_in[3];
    const float* in_proj_w     = (const float*)d_in[4];
    const float* in_proj_b     = (const float*)d_in[5];
    const float* out_proj_w    = (const float*)d_in[6];
    const float* out_proj_b    = (const float*)d_in[7];
    const float* pos_emb_glob  = (const float*)d_in[8];
    const float* w1_w          = (const float*)d_in[9];
    const float* w1_b          = (const float*)d_in[10];
    const float* w_2           = (const float*)d_in[11];
    const float* glu1_w        = (const float*)d_in[12];
    const float* glu1_b        = (const float*)d_in[13];
    const float* glu2_w        = (const float*)d_in[14];
    const int*   G_rows        = (const int*)d_in[15];
    const int*   G_cols        = (const int*)d_in[16];
    const float* G_vals        = (const float*)d_in[17];
    const int*   HG_rows       = (const int*)d_in[18];
    const int*   HG_cols       = (const int*)d_in[19];
    const float* HG_vals       = (const float*)d_in[20];
    const int*   seqs          = (const int*)d_in[21];
    const int*   masks         = (const int*)d_in[22];
    const float* adjs          = (const float*)d_in[23];
    const int*   uidx          = (const int*)d_in[24];
    const float* lens          = (const float*)d_in[25];
    const int*   rev_seqs      = (const int*)d_in[26];
    float* out = (float*)d_out;   // OUTPUT IS FLOAT32

    // ---- workspace layout; max offset used = 124,723,968 B ----
    char* base = (char*)d_ws;
    bf16*  nodes = (bf16*)base;                               // [0, 15,360,256)
    float* acc   = (float*)(base + 15360256);                 // [.., 46,080,768)
    char*  R     = base + 15360256 + 30720512;                // [46,080,768, 124,723,968)
    // layer-phase aliases inside R:
    bf16* P1 = (bf16*)R;          // BLD bf16
    bf16* P2 = P1 + BLD;
    bf16* P3 = P2 + BLD;
    // spmm-window aliases (P1/P2/P3 dead):
    float* Cbuf = (float*)R;                         // CN f32
    int2*  Gcv  = (int2*)(R + 30720000);             // NNZG*8 -> ends 46,080,000
    int*   Gptr = (int*)(R + 46080000);              // 60001*4
    int*   Gcur = (int*)(R + 46320016);              // 60000*4 (16B aligned)
    // global-phase aliases:
    bf16*  xg   = (bf16*)R;                          // PD bf16
    float* gtmp = (float*)(R + 12800000);            // PD f32
    float* accg = (float*)(R + 12800000 + 25600000); // PD f32 -> ends 64,000,000
    int2*  Hcv  = (int2*)(R + 64000000);             // NNZH*8 -> ends 76,800,000
    int*   Hptr = (int*)(R + 76800000);              // 50001*4
    int*   Hcur = (int*)(R + 77000016);              // 50000*4 (16B aligned)
    // head-phase aliases:
    float* H1f  = (float*)R;                         // BLD f32
    bf16*  nh   = (bf16*)(R + 52428800);             // BLD bf16 -> ends 78,643,200
    float* hs    = (float*)base;                     // small bufs in dead nodes region
    float* hproj = (float*)(base + 524288);
    float* posW  = (float*)(base + 1048576);
    float* betaB = (float*)(base + 1100288);

    auto gemm = [&](const bf16* A, const float* W, int wstride, int woff,
                    const float* bias, int boff, bf16* Cp, int act){
        k_mgemm<bf16,bf16><<<dim3(BL/128), dim3(256), 0, stream>>>(
            A, W, wstride, woff, bias, boff, Cp, act, nullptr, 0, nullptr);
    };

    // init: nodes (bf16) = nodes_emb, acc (f32) = nodes_emb
    k_init<<<dim3((NND+255)/256), dim3(256), 0, stream>>>(nodes, acc, nodes_emb, NND);

    for (int layer = 0; layer < 2; layer++){
        k_gather_b<<<dim3((BL*128+255)/256), dim3(256), 0, stream>>>(P1, nodes, seqs, BL);
        k_geo<<<dim3(BATCH), dim3(256), 0, stream>>>(P2, P1, adjs);
        gemm(P2, fc_geo_w, 128, 0, fc_geo_b, 0, P2, 1);   // relu, in-place (barrier-protected)
        k_tot<<<dim3((BLD+255)/256), dim3(256), 0, stream>>>(P3, P1, P2, pos_emb_local, BLD);
        gemm(P3, in_proj_w, 128, 0,       in_proj_b, 0,   P1, 0); // Q
        gemm(P3, in_proj_w, 128, 128*128, in_proj_b, 128, P2, 0); // K
        gemm(P3, in_proj_w, 128, 256*128, in_proj_b, 256, P3, 0); // V in-place
        k_attn<<<dim3(BATCH*8), dim3(256), 0, stream>>>(P1, P1, P2, P3);  // O over Q
        gemm(P1, out_proj_w, 128, 0, out_proj_b, 0, P2, 0);
        k_mean_users<<<dim3(BATCH), dim3(128), 0, stream>>>(nodes, P2, uidx);
        // ---- build G CSR (scratch lives in dead P2/P3 space; rebuilt each layer) ----
        k_zero<<<dim3((15000+255)/256), dim3(256), 0, stream>>>((float*)Gcur, 15000); // 60000 ints
        k_hist<<<dim3(NNZG/256), dim3(256), 0, stream>>>(Gcur, G_rows, NNZG);
        k_scan<<<dim3(1), dim3(1024), 0, stream>>>(Gcur, Gptr, 60000);
        k_scatter<<<dim3(NNZG/256), dim3(256), 0, stream>>>(Gcv, Gcur, G_rows, G_cols, G_vals, NNZG);
        k_spmm_csr<<<dim3(60000/4), dim3(256), 0, stream>>>(Cbuf, Gptr, Gcv, nodes, 60000);
        k_commit<<<dim3((CN+255)/256), dim3(256), 0, stream>>>(nodes, acc, Cbuf, CN);
    }
    // local = acc/3
    k_scale<<<dim3((NND+255)/256), dim3(256), 0, stream>>>(acc, NND);

    // global hypergraph branch
    k_initg<<<dim3((PD+255)/256), dim3(256), 0, stream>>>(xg, accg, nodes_emb, PD);
    k_zero<<<dim3((12500+255)/256), dim3(256), 0, stream>>>((float*)Hcur, 12500); // 50000 ints
    k_hist<<<dim3(NNZH/256), dim3(256), 0, stream>>>(Hcur, HG_rows, NNZH);
    k_scan<<<dim3(1), dim3(1024), 0, stream>>>(Hcur, Hptr, 50000);
    k_scatter<<<dim3(NNZH/256), dim3(256), 0, stream>>>(Hcv, Hcur, HG_rows, HG_cols, HG_vals, NNZH);
    for (int it = 0; it < 2; it++){
        k_spmm_csr<<<dim3(50000/4), dim3(256), 0, stream>>>(gtmp, Hptr, Hcv, xg, 50000);
        k_commit2<<<dim3((PD+255)/256), dim3(256), 0, stream>>>(xg, accg, gtmp, PD);
    }
    // fusion: pois rows of acc += accg/3, emit pois output (f32, offset in f32 elems)
    k_fusion<<<dim3((PD+255)/256), dim3(256), 0, stream>>>(acc + (size_t)NUSERS*128, accg, out + BATCH*128, PD);

    // ===== head (f32 path) =====
    k_gather_f<<<dim3((BL*128+255)/256), dim3(256), 0, stream>>>(H1f, acc, rev_seqs, BL);
    k_hs<<<dim3(BATCH), dim3(128), 0, stream>>>(hs, H1f, lens);
    // hproj = hs @ glu2_w^T  (f32-A 3-term MFMA path)
    k_mgemm<float,float><<<dim3(BATCH/128), dim3(256), 0, stream>>>(
        hs, glu2_w, 128, 0, nullptr, 0, hproj, 0, nullptr, 0, nullptr);
    k_posw<<<dim3(SEQL+1), dim3(128), 0, stream>>>(posW, pos_emb_glob, w1_w);
    // nh1 = tanh(H1f @ w1_w[:,128:]^T + posW[pidx] + w1_b)
    k_mgemm<float,bf16><<<dim3(BL/128), dim3(256), 0, stream>>>(
        H1f, w1_w, 256, 128, w1_b, 0, nh, 2, posW, 1, masks);
    // nh2 = sigmoid(nh @ glu1_w^T + glu1_b + hproj[b])  (in-place, barrier-protected)
    k_mgemm<bf16,bf16><<<dim3(BL/128), dim3(256), 0, stream>>>(
        nh, glu1_w, 128, 0, glu1_b, 0, nh, 3, hproj, 2, nullptr);
    k_beta<<<dim3(BL), dim3(128), 0, stream>>>(betaB, nh, w_2);
    k_final<<<dim3(BATCH), dim3(128), 0, stream>>>(out, betaB, H1f, acc, uidx);
}

// Round 5
// 2852.994 us; speedup vs baseline: 8.5623x; 1.3897x over previous
//
#include <hip/hip_runtime.h>
#include <hip/hip_bf16.h>
#include <math.h>

typedef __hip_bfloat16 bf16;

__device__ __forceinline__ float b2f(bf16 x){ return __bfloat162float(x); }
__device__ __forceinline__ bf16  f2b(float x){ return __float2bfloat16(x); }

// raw-bits bf16 helpers (RNE, finite inputs)
__device__ __forceinline__ short f2bs(float f){
    unsigned u = __float_as_uint(f);
    u += 0x7fffu + ((u >> 16) & 1u);
    return (short)(u >> 16);
}
__device__ __forceinline__ float bs2f(short s){
    return __uint_as_float(((unsigned)(unsigned short)s) << 16);
}

#define NUSERS   10000
#define NPOIS    50000
#define SEQL     100
#define NNODES   60001
#define BATCH    1024
#define NNZG     1920000
#define NNZH     1600000
#define BL       (BATCH*SEQL)          // 102400
#define BLD      (BL*128)              // 13,107,200 elems
#define NND      (NNODES*128)          // 7,680,128
#define CN       (60000*128)           // 7,680,000
#define PD       (NPOIS*128)           // 6,400,000

__device__ __forceinline__ void  stc(bf16* p,  float v){ *p = f2b(v); }
__device__ __forceinline__ void  stc(float* p, float v){ *p = v; }

typedef __attribute__((ext_vector_type(8))) short s16x8;
typedef __attribute__((ext_vector_type(4))) float f32x4;

// ---------- zero-fill (16B granules) ----------
__global__ __launch_bounds__(256) void k_zero(float* __restrict__ p, int n4){
    int i = blockIdx.x*256 + threadIdx.x;
    if (i < n4) ((float4*)p)[i] = make_float4(0.f,0.f,0.f,0.f);
}

// ---------- init: nodes(bf16)=src, acc(f32)=src ----------
__global__ __launch_bounds__(256) void k_init(bf16* __restrict__ nodes, float* __restrict__ acc,
                                              const float* __restrict__ src, int n){
    int i = blockIdx.x*256 + threadIdx.x;
    if (i >= n) return;
    float v = src[i];
    nodes[i] = f2b(v); acc[i] = v;
}

// ---------- row gather bf16 table -> bf16 dst ----------
__global__ __launch_bounds__(256) void k_gather_b(bf16* __restrict__ dst,
                                                  const bf16* __restrict__ table,
                                                  const int* __restrict__ idx, int rows){
    int gid = blockIdx.x*256 + threadIdx.x;
    if (gid >= rows*128) return;
    int r = gid >> 7, c = gid & 127;
    dst[(size_t)r*128 + c] = table[(size_t)idx[r]*128 + c];
}

// ---------- row gather f32 table -> f32 dst ----------
__global__ __launch_bounds__(256) void k_gather_f(float* __restrict__ dst,
                                                  const float* __restrict__ table,
                                                  const int* __restrict__ idx, int rows){
    int gid = blockIdx.x*256 + threadIdx.x;
    if (gid >= rows*128) return;
    int r = gid >> 7, c = gid & 127;
    dst[(size_t)r*128 + c] = table[(size_t)idx[r]*128 + c];
}

// ================= MFMA geo: geo[b,l,c] = sum_s adj[b,l,s]*seq[b,s,c] =================
// A = adj (f32 -> bf16 hi/lo, 2 MFMA terms), B = seq^T staged in LDS (bf16 exact).
__global__ __launch_bounds__(256) void k_mgeo(bf16* __restrict__ geo,
                                              const bf16* __restrict__ seq,
                                              const float* __restrict__ adj){
    __shared__ short st[128*104];      // seq^T, pitch 104 (16B-aligned rows)
    int b = blockIdx.x, tid = threadIdx.x;
    const short* src = (const short*)(seq + (size_t)b*SEQL*128);
    for (int i = tid; i < SEQL*128; i += 256){ int j = i>>7, c = i&127; st[c*104 + j] = src[i]; }
    for (int i = tid; i < 128*4; i += 256){ int c = i>>2, r = i&3; st[c*104 + 100 + r] = 0; }
    __syncthreads();
    int wv = tid>>6, lane = tid&63, lr = lane&15, lk = lane>>4;
    const s16x8 zf = {0,0,0,0,0,0,0,0};
    // B-frags: wave's two 16-col tiles, 4 k-chunks, held in VGPRs
    s16x8 bfr[2][4];
    #pragma unroll
    for (int t = 0; t < 2; t++){
        int nt = wv*2 + t;
        #pragma unroll
        for (int kc = 0; kc < 4; kc++)
            bfr[t][kc] = *(const s16x8*)&st[(nt*16+lr)*104 + kc*32 + lk*8];
    }
    const float* ab = adj + (size_t)b*SEQL*SEQL;
    for (int mt = 0; mt < 7; mt++){
        int ar = min(mt*16 + lr, SEQL-1);          // clamp pad rows (discarded at store)
        s16x8 ah[4], al[4];
        #pragma unroll
        for (int kc = 0; kc < 4; kc++){
            float av[8] = {0,0,0,0,0,0,0,0};
            if (kc < 3){
                const float* ap = ab + (size_t)ar*SEQL + kc*32 + lk*8;
                float4 a0 = *(const float4*)ap;
                float4 a1 = *(const float4*)(ap + 4);
                av[0]=a0.x; av[1]=a0.y; av[2]=a0.z; av[3]=a0.w;
                av[4]=a1.x; av[5]=a1.y; av[6]=a1.z; av[7]=a1.w;
            } else if (lk == 0){
                float4 a0 = *(const float4*)(ab + (size_t)ar*SEQL + 96);
                av[0]=a0.x; av[1]=a0.y; av[2]=a0.z; av[3]=a0.w;   // k=96..99; pad stays 0
            }
            s16x8 h = zf, l = zf;
            #pragma unroll
            for (int j = 0; j < 8; j++){
                short hb = f2bs(av[j]);
                h[j] = hb;
                l[j] = f2bs(av[j] - bs2f(hb));
            }
            ah[kc] = h; al[kc] = l;
        }
        f32x4 c0 = {0.f,0.f,0.f,0.f}, c1 = {0.f,0.f,0.f,0.f};
        #pragma unroll
        for (int kc = 0; kc < 4; kc++){
            c0 = __builtin_amdgcn_mfma_f32_16x16x32_bf16(ah[kc], bfr[0][kc], c0, 0,0,0);
            c0 = __builtin_amdgcn_mfma_f32_16x16x32_bf16(al[kc], bfr[0][kc], c0, 0,0,0);
            c1 = __builtin_amdgcn_mfma_f32_16x16x32_bf16(ah[kc], bfr[1][kc], c1, 0,0,0);
            c1 = __builtin_amdgcn_mfma_f32_16x16x32_bf16(al[kc], bfr[1][kc], c1, 0,0,0);
        }
        #pragma unroll
        for (int t = 0; t < 2; t++){
            f32x4 cc = t ? c1 : c0;
            int col = wv*32 + t*16 + lr;
            #pragma unroll
            for (int r = 0; r < 4; r++){
                int row = mt*16 + lk*4 + r;
                if (row < SEQL)
                    geo[(size_t)b*SEQL*128 + (size_t)row*128 + col] = f2b(cc[r]);
            }
        }
    }
}

// ---------- tot = seq + geo + pos_local[l+1] ----------
__global__ __launch_bounds__(256) void k_tot(bf16* __restrict__ tot,
                                             const bf16* __restrict__ seq,
                                             const bf16* __restrict__ geo,
                                             const float* __restrict__ posl, int n){
    int i = blockIdx.x*256 + threadIdx.x;
    if (i >= n) return;
    int c = i & 127, bl = i >> 7, l = bl % SEQL;
    tot[i] = f2b(b2f(seq[i]) + b2f(geo[i]) + posl[(l+1)*128 + c]);
}

// ================= MFMA GEMM =================
// C[M,128] = epilogue( A[M,128] @ W[n, wstride; +woff]^T )
// W f32 -> bf16 hi+lo in-register. TA=bf16: 2 terms; TA=float: 3 terms.
// act: 0=none 1=relu 2=tanh 3=sigmoid
// addmode 1: += add1[((m%SEQL)+1)*masks[m]*128+n]; 2: += add1[(m/SEQL)*128+n]
// In-place safe via per-stripe __syncthreads.
template<typename TA, typename TC>
__global__ __launch_bounds__(256) void k_mgemm(const TA* __restrict__ A,
                                               const float* __restrict__ W, int wstride, int woff,
                                               const float* __restrict__ bias, int boff,
                                               TC* __restrict__ C, int act,
                                               const float* __restrict__ add1, int addmode,
                                               const int* __restrict__ masks){
    constexpr bool A_BF = (sizeof(TA) == 2);
    int tid  = threadIdx.x;
    int wv   = tid >> 6;
    int lane = tid & 63;
    int lr   = lane & 15;
    int lk   = lane >> 4;
    int n0   = wv * 32;

    s16x8 wh[2][4], wl[2][4];
    #pragma unroll
    for (int t = 0; t < 2; t++){
        #pragma unroll
        for (int ks = 0; ks < 4; ks++){
            const float* wp = W + (size_t)(n0 + t*16 + lr)*wstride + woff + ks*32 + lk*8;
            float4 w0 = *(const float4*)(wp);
            float4 w1 = *(const float4*)(wp + 4);
            float wf[8] = {w0.x,w0.y,w0.z,w0.w,w1.x,w1.y,w1.z,w1.w};
            s16x8 h, l;
            #pragma unroll
            for (int j = 0; j < 8; j++){
                short hb = f2bs(wf[j]);
                h[j] = hb;
                l[j] = f2bs(wf[j] - bs2f(hb));
            }
            wh[t][ks] = h; wl[t][ks] = l;
        }
    }

    size_t mblk = (size_t)blockIdx.x * 128;
    for (int it = 0; it < 8; it++){
        size_t m0 = mblk + (size_t)it*16;
        s16x8 ah[4], al[4];
        #pragma unroll
        for (int ks = 0; ks < 4; ks++){
            if constexpr (A_BF){
                ah[ks] = *(const s16x8*)((const short*)A + (m0 + lr)*128 + ks*32 + lk*8);
            } else {
                const float* ap = (const float*)A + (m0 + lr)*128 + ks*32 + lk*8;
                float4 a0 = *(const float4*)(ap);
                float4 a1 = *(const float4*)(ap + 4);
                float av[8] = {a0.x,a0.y,a0.z,a0.w,a1.x,a1.y,a1.z,a1.w};
                s16x8 h, l;
                #pragma unroll
                for (int j = 0; j < 8; j++){
                    short hb = f2bs(av[j]);
                    h[j] = hb;
                    l[j] = f2bs(av[j] - bs2f(hb));
                }
                ah[ks] = h; al[ks] = l;
            }
        }
        __syncthreads();   // in-place safety: all reads of stripe before any writes
        f32x4 c0 = {0.f,0.f,0.f,0.f}, c1 = {0.f,0.f,0.f,0.f};
        #pragma unroll
        for (int ks = 0; ks < 4; ks++){
            c0 = __builtin_amdgcn_mfma_f32_16x16x32_bf16(ah[ks], wh[0][ks], c0, 0, 0, 0);
            c0 = __builtin_amdgcn_mfma_f32_16x16x32_bf16(ah[ks], wl[0][ks], c0, 0, 0, 0);
            c1 = __builtin_amdgcn_mfma_f32_16x16x32_bf16(ah[ks], wh[1][ks], c1, 0, 0, 0);
            c1 = __builtin_amdgcn_mfma_f32_16x16x32_bf16(ah[ks], wl[1][ks], c1, 0, 0, 0);
            if constexpr (!A_BF){
                c0 = __builtin_amdgcn_mfma_f32_16x16x32_bf16(al[ks], wh[0][ks], c0, 0, 0, 0);
                c1 = __builtin_amdgcn_mfma_f32_16x16x32_bf16(al[ks], wh[1][ks], c1, 0, 0, 0);
            }
        }
        #pragma unroll
        for (int t = 0; t < 2; t++){
            f32x4 cc = t ? c1 : c0;
            int c = n0 + t*16 + lr;
            float bv = bias ? bias[boff + c] : 0.f;
            #pragma unroll
            for (int r4 = 0; r4 < 4; r4++){
                int m = (int)m0 + lk*4 + r4;
                float v = cc[r4] + bv;
                if (addmode == 1){
                    int l = m % SEQL;
                    int p = (l+1) * masks[m];
                    v += add1[p*128 + c];
                } else if (addmode == 2){
                    v += add1[(m/SEQL)*128 + c];
                }
                if (act == 1) v = fmaxf(v, 0.f);
                else if (act == 2) v = tanhf(v);
                else if (act == 3) v = 1.f/(1.f+__expf(-v));
                stc(&C[(size_t)m*128 + c], v);
            }
        }
    }
}

// ================= MFMA attention =================
// One block per b; 4 waves x 2 heads. d_head=16 -> K=32 MFMA with upper half zero.
// Softmax wave-parallel (quarter shfl reductions). P stored bf16 hi+lo (precision).
// O aliases Q's plane: each wave touches only its own heads' columns.
// NOTE: no __restrict__ (o/Qq alias). Pad rows clamped to stay in-bounds.
__global__ __launch_bounds__(256) void k_mattn(bf16* o, const bf16* Qq,
                                               const bf16* Qk, const bf16* Qv){
    __shared__ short Vt[128*104];      // V^T, pitch 104
    __shared__ short Ph[4][16*136];    // per-wave P stripe (hi), pitch 136
    __shared__ short Pl[4][16*136];    // per-wave P stripe (lo)
    int b = blockIdx.x, tid = threadIdx.x;
    const short* vsrc = (const short*)(Qv + (size_t)b*SEQL*128);
    for (int i = tid; i < SEQL*128; i += 256){ int j = i>>7, c = i&127; Vt[c*104 + j] = vsrc[i]; }
    for (int i = tid; i < 128*4; i += 256){ int c = i>>2, r = i&3; Vt[c*104 + 100 + r] = 0; }
    int wv = tid>>6, lane = tid&63, lr = lane&15, lk = lane>>4;
    short* phw = Ph[wv];
    short* plw = Pl[wv];
    for (int i = lane; i < 16*136; i += 64){ phw[i] = 0; plw[i] = 0; }
    __syncthreads();

    const s16x8 zf = {0,0,0,0,0,0,0,0};
    size_t rowbase = (size_t)b*SEQL*128;
    bool kreal = (lk < 2);
    for (int hh = 0; hh < 2; hh++){
        int h = wv*2 + hh;
        int hd = h*16 + lk*8;
        // K-frags (held in regs across all m-tiles); rows clamped to <SEQL
        s16x8 kf[7];
        #pragma unroll
        for (int nt = 0; nt < 7; nt++){
            int kr = min(nt*16 + lr, SEQL-1);
            kf[nt] = kreal ? *(const s16x8*)((const short*)Qk + rowbase + (size_t)kr*128 + hd) : zf;
        }
        // V-frags
        s16x8 vf[4];
        #pragma unroll
        for (int kc = 0; kc < 4; kc++)
            vf[kc] = *(const s16x8*)&Vt[(h*16+lr)*104 + kc*32 + lk*8];

        for (int mt = 0; mt < 7; mt++){
            int qr = min(mt*16 + lr, SEQL-1);
            s16x8 qf = kreal ? *(const s16x8*)((const short*)Qq + rowbase + (size_t)qr*128 + hd) : zf;
            f32x4 sc[7];
            #pragma unroll
            for (int nt = 0; nt < 7; nt++){
                f32x4 z = {0.f,0.f,0.f,0.f};
                sc[nt] = __builtin_amdgcn_mfma_f32_16x16x32_bf16(qf, kf[nt], z, 0,0,0);
            }
            float mx[4] = {-1e30f,-1e30f,-1e30f,-1e30f};
            #pragma unroll
            for (int nt = 0; nt < 7; nt++){
                bool masked = (nt == 6) && (lr >= 4);   // cols >= 100
                #pragma unroll
                for (int r = 0; r < 4; r++){
                    float s = masked ? -1e30f : sc[nt][r]*0.25f;
                    sc[nt][r] = s;
                    mx[r] = fmaxf(mx[r], s);
                }
            }
            #pragma unroll
            for (int m = 1; m < 16; m <<= 1){
                #pragma unroll
                for (int r = 0; r < 4; r++) mx[r] = fmaxf(mx[r], __shfl_xor(mx[r], m));
            }
            float sm[4] = {0.f,0.f,0.f,0.f};
            #pragma unroll
            for (int nt = 0; nt < 7; nt++){
                #pragma unroll
                for (int r = 0; r < 4; r++){
                    float p = __expf(sc[nt][r] - mx[r]);
                    sc[nt][r] = p; sm[r] += p;
                }
            }
            #pragma unroll
            for (int m = 1; m < 16; m <<= 1){
                #pragma unroll
                for (int r = 0; r < 4; r++) sm[r] += __shfl_xor(sm[r], m);
            }
            float inv[4];
            #pragma unroll
            for (int r = 0; r < 4; r++) inv[r] = 1.f/sm[r];
            // write P hi/lo: row = lk*4+r, col = nt*16+lr
            #pragma unroll
            for (int nt = 0; nt < 7; nt++){
                #pragma unroll
                for (int r = 0; r < 4; r++){
                    float p = sc[nt][r]*inv[r];
                    short hb = f2bs(p);
                    int pa = (lk*4+r)*136 + nt*16 + lr;
                    phw[pa] = hb;
                    plw[pa] = f2bs(p - bs2f(hb));
                }
            }
            // PV: A = P rows (row=lr), B = vf
            f32x4 oa = {0.f,0.f,0.f,0.f};
            #pragma unroll
            for (int kc = 0; kc < 4; kc++){
                s16x8 pah = *(const s16x8*)&phw[lr*136 + kc*32 + lk*8];
                s16x8 pal = *(const s16x8*)&plw[lr*136 + kc*32 + lk*8];
                oa = __builtin_amdgcn_mfma_f32_16x16x32_bf16(pah, vf[kc], oa, 0,0,0);
                oa = __builtin_amdgcn_mfma_f32_16x16x32_bf16(pal, vf[kc], oa, 0,0,0);
            }
            // store O rows < 100 (col = h*16+lr, row = mt*16+lk*4+r)
            #pragma unroll
            for (int r = 0; r < 4; r++){
                int row = mt*16 + lk*4 + r;
                if (row < SEQL)
                    ((short*)o)[rowbase + (size_t)row*128 + h*16 + lr] = f2bs(oa[r]);
            }
        }
    }
}

// ---------- users = mean_l(o2) -> nodes[uidx[b]] ----------
__global__ __launch_bounds__(128) void k_mean_users(bf16* __restrict__ nodes,
                                                    const bf16* __restrict__ o,
                                                    const int* __restrict__ uidx){
    int b = blockIdx.x, c = threadIdx.x;
    const bf16* p = o + (size_t)b*SEQL*128 + c;
    float sum = 0.f;
    for (int l = 0; l < SEQL; l++) sum += b2f(p[l*128]);
    nodes[(size_t)uidx[b]*128 + c] = f2b(sum * (1.f/(float)SEQL));
}

// ================= CSR build + row-wave SpMM =================

__global__ __launch_bounds__(256) void k_hist(int* __restrict__ cnt,
                                              const int* __restrict__ rows, int nnz){
    int e = blockIdx.x*256 + threadIdx.x;
    if (e < nnz) atomicAdd(&cnt[rows[e]], 1);
}

__global__ __launch_bounds__(1024) void k_scan(int* __restrict__ cnt,
                                               int* __restrict__ rowptr, int nrows){
    __shared__ int part[1024];
    int tid = threadIdx.x;
    int chunk = (nrows + 1023) >> 10;
    int s = tid*chunk, e = min(s+chunk, nrows);
    int sum = 0;
    for (int i = s; i < e; i++) sum += cnt[i];
    part[tid] = sum;
    __syncthreads();
    for (int off = 1; off < 1024; off <<= 1){
        int add = (tid >= off) ? part[tid-off] : 0;
        __syncthreads();
        part[tid] += add;
        __syncthreads();
    }
    int run = part[tid] - sum;
    for (int i = s; i < e; i++){
        int c = cnt[i];
        rowptr[i] = run;
        cnt[i]    = run;
        run += c;
    }
    if (tid == 0) rowptr[nrows] = part[1023];
}

__global__ __launch_bounds__(256) void k_scatter(int2* __restrict__ cv,
                                                 int* __restrict__ cur,
                                                 const int* __restrict__ rows,
                                                 const int* __restrict__ cols,
                                                 const float* __restrict__ vals, int nnz){
    int e = blockIdx.x*256 + threadIdx.x;
    if (e >= nnz) return;
    int p = atomicAdd(&cur[rows[e]], 1);
    cv[p] = make_int2(cols[e], __float_as_int(vals[e]));
}

__global__ __launch_bounds__(256) void k_spmm_csr(float* __restrict__ y,
                                                  const int* __restrict__ rowptr,
                                                  const int2* __restrict__ cv,
                                                  const bf16* __restrict__ x, int nrows){
    int row = blockIdx.x*4 + (threadIdx.x >> 6);
    if (row >= nrows) return;
    int lane = threadIdx.x & 63;
    int s = rowptr[row], e = rowptr[row+1];
    float a0 = 0.f, a1 = 0.f;
    for (int i = s; i < e; i++){
        int2 p = cv[i];
        float v = __int_as_float(p.y);
        unsigned u = *(const unsigned*)(x + (size_t)p.x*128 + lane*2);
        a0 += v * __uint_as_float((u & 0xffffu) << 16);
        a1 += v * __uint_as_float(u & 0xffff0000u);
    }
    float* yp = y + (size_t)row*128 + lane*2;
    *(float2*)yp = make_float2(a0, a1);
}

// ---------- nodes(bf16)[:60000] = Cbuf; acc(f32) += Cbuf ----------
__global__ __launch_bounds__(256) void k_commit(bf16* __restrict__ nodes, float* __restrict__ acc,
                                                const float* __restrict__ Cb, int n){
    int i = blockIdx.x*256 + threadIdx.x;
    if (i >= n) return;
    float v = Cb[i];
    nodes[i] = f2b(v);
    acc[i] += v;
}

__global__ __launch_bounds__(256) void k_scale(float* __restrict__ a, int n){
    int i = blockIdx.x*256 + threadIdx.x;
    if (i < n) a[i] *= (1.f/3.f);
}

// ---------- global branch init ----------
__global__ __launch_bounds__(256) void k_initg(bf16* __restrict__ xg, float* __restrict__ accg,
                                               const float* __restrict__ ne, int n){
    int i = blockIdx.x*256 + threadIdx.x;
    if (i >= n) return;
    float v = ne[(size_t)NUSERS*128 + i];
    xg[i] = f2b(v); accg[i] = v;
}

__global__ __launch_bounds__(256) void k_commit2(bf16* __restrict__ xg, float* __restrict__ accg,
                                                 const float* __restrict__ tmp, int n){
    int i = blockIdx.x*256 + threadIdx.x;
    if (i >= n) return;
    float v = tmp[i];
    xg[i] = f2b(v);
    accg[i] += v;
}

// ---------- fusion: acc_poi += accg/3; emit pois output (f32!) ----------
__global__ __launch_bounds__(256) void k_fusion(float* __restrict__ accP,
                                                const float* __restrict__ accg,
                                                float* __restrict__ outp, int n){
    int i = blockIdx.x*256 + threadIdx.x;
    if (i >= n) return;
    float v = accP[i] + accg[i]*(1.f/3.f);
    accP[i] = v;
    outp[i] = v;
}

// ================= HEAD =================

__global__ __launch_bounds__(128) void k_hs(float* __restrict__ hs, const float* __restrict__ sh,
                                            const float* __restrict__ lens){
    int b = blockIdx.x, c = threadIdx.x;
    const float* p = sh + (size_t)b*SEQL*128 + c;
    float sum = 0.f;
    for (int l = 0; l < SEQL; l++) sum += p[l*128];
    hs[b*128 + c] = sum / lens[b];
}

__global__ __launch_bounds__(128) void k_posw(float* __restrict__ posW,
                                              const float* __restrict__ pg,
                                              const float* __restrict__ w1w){
    __shared__ float sm[128];
    int p = blockIdx.x, n = threadIdx.x;
    sm[n] = pg[p*128 + n];
    __syncthreads();
    const float* wr = w1w + (size_t)n*256;
    float s = 0.f;
    for (int k = 0; k < 128; k++) s += sm[k]*wr[k];
    posW[p*128 + n] = s;
}

// ---------- beta: per-wave reduction, 4 rows/block ----------
__global__ __launch_bounds__(256) void k_beta(float* __restrict__ beta,
                                              const bf16* __restrict__ nh,
                                              const float* __restrict__ w2){
    int m = blockIdx.x*4 + (threadIdx.x >> 6);
    int lane = threadIdx.x & 63;
    float v = b2f(nh[(size_t)m*128 + lane]) * w2[lane]
            + b2f(nh[(size_t)m*128 + 64 + lane]) * w2[64 + lane];
    #pragma unroll
    for (int s = 1; s < 64; s <<= 1) v += __shfl_xor(v, s);
    if (lane == 0) beta[m] = v;
}

__global__ __launch_bounds__(128) void k_final(float* __restrict__ out,
                                               const float* __restrict__ beta,
                                               const float* __restrict__ seqh,
                                               const float* __restrict__ acc,
                                               const int* __restrict__ uidx){
    int b = blockIdx.x, c = threadIdx.x;
    const float* sh = seqh + (size_t)b*SEQL*128 + c;
    const float* bp = beta + b*SEQL;
    float sel = 0.f;
    for (int l = 0; l < SEQL; l++) sel += bp[l]*sh[l*128];
    out[b*128 + c] = sel + acc[(size_t)uidx[b]*128 + c];
}

extern "C" void kernel_launch(void* const* d_in, const int* in_sizes, int n_in,
                              void* d_out, int out_size, void* d_ws, size_t ws_size,
                              hipStream_t stream){
    const float* nodes_emb     = (const float*)d_in[0];
    const float* pos_emb_local = (const float*)d_in[1];
    const float* fc_geo_w      = (const float*)d_in[2];
    const float* fc_geo_b      = (const float*)d_in[3];
    const float* in_proj_w     = (const float*)d_in[4];
    const float* in_proj_b     = (const float*)d_in[5];
    const float* out_proj_w    = (const float*)d_in[6];
    const float* out_proj_b    = (const float*)d_in[7];
    const float* pos_emb_glob  = (const float*)d_in[8];
    const float* w1_w          = (const float*)d_in[9];
    const float* w1_b          = (const float*)d_in[10];
    const float* w_2           = (const float*)d_in[11];
    const float* glu1_w        = (const float*)d_in[12];
    const float* glu1_b        = (const float*)d_in[13];
    const float* glu2_w        = (const float*)d_in[14];
    const int*   G_rows        = (const int*)d_in[15];
    const int*   G_cols        = (const int*)d_in[16];
    const float* G_vals        = (const float*)d_in[17];
    const int*   HG_rows       = (const int*)d_in[18];
    const int*   HG_cols       = (const int*)d_in[19];
    const float* HG_vals       = (const float*)d_in[20];
    const int*   seqs          = (const int*)d_in[21];
    const int*   masks         = (const int*)d_in[22];
    const float* adjs          = (const float*)d_in[23];
    const int*   uidx          = (const int*)d_in[24];
    const float* lens          = (const float*)d_in[25];
    const int*   rev_seqs      = (const int*)d_in[26];
    float* out = (float*)d_out;   // OUTPUT IS FLOAT32

    // ---- workspace layout; max offset used = 124,723,968 B ----
    char* base = (char*)d_ws;
    bf16*  nodes = (bf16*)base;                               // [0, 15,360,256)
    float* acc   = (float*)(base + 15360256);                 // [.., 46,080,768)
    char*  R     = base + 15360256 + 30720512;                // [46,080,768, 124,723,968)
    // layer-phase aliases inside R:
    bf16* P1 = (bf16*)R;          // BLD bf16
    bf16* P2 = P1 + BLD;
    bf16* P3 = P2 + BLD;
    // spmm-window aliases (P1/P2/P3 dead):
    float* Cbuf = (float*)R;                         // CN f32
    int2*  Gcv  = (int2*)(R + 30720000);             // NNZG*8 -> ends 46,080,000
    int*   Gptr = (int*)(R + 46080000);              // 60001*4
    int*   Gcur = (int*)(R + 46320016);              // 60000*4 (16B aligned)
    // global-phase aliases:
    bf16*  xg   = (bf16*)R;                          // PD bf16
    float* gtmp = (float*)(R + 12800000);            // PD f32
    float* accg = (float*)(R + 12800000 + 25600000); // PD f32 -> ends 64,000,000
    int2*  Hcv  = (int2*)(R + 64000000);             // NNZH*8 -> ends 76,800,000
    int*   Hptr = (int*)(R + 76800000);              // 50001*4
    int*   Hcur = (int*)(R + 77000016);              // 50000*4 (16B aligned)
    // head-phase aliases:
    float* H1f  = (float*)R;                         // BLD f32
    bf16*  nh   = (bf16*)(R + 52428800);             // BLD bf16 -> ends 78,643,200
    float* hs    = (float*)base;                     // small bufs in dead nodes region
    float* hproj = (float*)(base + 524288);
    float* posW  = (float*)(base + 1048576);
    float* betaB = (float*)(base + 1100288);

    auto gemm = [&](const bf16* A, const float* W, int wstride, int woff,
                    const float* bias, int boff, bf16* Cp, int act){
        k_mgemm<bf16,bf16><<<dim3(BL/128), dim3(256), 0, stream>>>(
            A, W, wstride, woff, bias, boff, Cp, act, nullptr, 0, nullptr);
    };

    // init: nodes (bf16) = nodes_emb, acc (f32) = nodes_emb
    k_init<<<dim3((NND+255)/256), dim3(256), 0, stream>>>(nodes, acc, nodes_emb, NND);

    for (int layer = 0; layer < 2; layer++){
        k_gather_b<<<dim3((BL*128+255)/256), dim3(256), 0, stream>>>(P1, nodes, seqs, BL);
        k_mgeo<<<dim3(BATCH), dim3(256), 0, stream>>>(P2, P1, adjs);
        gemm(P2, fc_geo_w, 128, 0, fc_geo_b, 0, P2, 1);   // relu, in-place (barrier-protected)
        k_tot<<<dim3((BLD+255)/256), dim3(256), 0, stream>>>(P3, P1, P2, pos_emb_local, BLD);
        gemm(P3, in_proj_w, 128, 0,       in_proj_b, 0,   P1, 0); // Q
        gemm(P3, in_proj_w, 128, 128*128, in_proj_b, 128, P2, 0); // K
        gemm(P3, in_proj_w, 128, 256*128, in_proj_b, 256, P3, 0); // V in-place
        k_mattn<<<dim3(BATCH), dim3(256), 0, stream>>>(P1, P1, P2, P3);   // O over Q
        gemm(P1, out_proj_w, 128, 0, out_proj_b, 0, P2, 0);
        k_mean_users<<<dim3(BATCH), dim3(128), 0, stream>>>(nodes, P2, uidx);
        // ---- build G CSR (scratch lives in dead P2/P3 space; rebuilt each layer) ----
        k_zero<<<dim3((15000+255)/256), dim3(256), 0, stream>>>((float*)Gcur, 15000); // 60000 ints
        k_hist<<<dim3(NNZG/256), dim3(256), 0, stream>>>(Gcur, G_rows, NNZG);
        k_scan<<<dim3(1), dim3(1024), 0, stream>>>(Gcur, Gptr, 60000);
        k_scatter<<<dim3(NNZG/256), dim3(256), 0, stream>>>(Gcv, Gcur, G_rows, G_cols, G_vals, NNZG);
        k_spmm_csr<<<dim3(60000/4), dim3(256), 0, stream>>>(Cbuf, Gptr, Gcv, nodes, 60000);
        k_commit<<<dim3((CN+255)/256), dim3(256), 0, stream>>>(nodes, acc, Cbuf, CN);
    }
    // local = acc/3
    k_scale<<<dim3((NND+255)/256), dim3(256), 0, stream>>>(acc, NND);

    // global hypergraph branch
    k_initg<<<dim3((PD+255)/256), dim3(256), 0, stream>>>(xg, accg, nodes_emb, PD);
    k_zero<<<dim3((12500+255)/256), dim3(256), 0, stream>>>((float*)Hcur, 12500); // 50000 ints
    k_hist<<<dim3(NNZH/256), dim3(256), 0, stream>>>(Hcur, HG_rows, NNZH);
    k_scan<<<dim3(1), dim3(1024), 0, stream>>>(Hcur, Hptr, 50000);
    k_scatter<<<dim3(NNZH/256), dim3(256), 0, stream>>>(Hcv, Hcur, HG_rows, HG_cols, HG_vals, NNZH);
    for (int it = 0; it < 2; it++){
        k_spmm_csr<<<dim3(50000/4), dim3(256), 0, stream>>>(gtmp, Hptr, Hcv, xg, 50000);
        k_commit2<<<dim3((PD+255)/256), dim3(256), 0, stream>>>(xg, accg, gtmp, PD);
    }
    // fusion: pois rows of acc += accg/3, emit pois output (f32, offset in f32 elems)
    k_fusion<<<dim3((PD+255)/256), dim3(256), 0, stream>>>(acc + (size_t)NUSERS*128, accg, out + BATCH*128, PD);

    // ===== head (f32 path) =====
    k_gather_f<<<dim3((BL*128+255)/256), dim3(256), 0, stream>>>(H1f, acc, rev_seqs, BL);
    k_hs<<<dim3(BATCH), dim3(128), 0, stream>>>(hs, H1f, lens);
    // hproj = hs @ glu2_w^T  (f32-A 3-term MFMA path)
    k_mgemm<float,float><<<dim3(BATCH/128), dim3(256), 0, stream>>>(
        hs, glu2_w, 128, 0, nullptr, 0, hproj, 0, nullptr, 0, nullptr);
    k_posw<<<dim3(SEQL+1), dim3(128), 0, stream>>>(posW, pos_emb_glob, w1_w);
    // nh1 = tanh(H1f @ w1_w[:,128:]^T + posW[pidx] + w1_b)
    k_mgemm<float,bf16><<<dim3(BL/128), dim3(256), 0, stream>>>(
        H1f, w1_w, 256, 128, w1_b, 0, nh, 2, posW, 1, masks);
    // nh2 = sigmoid(nh @ glu1_w^T + glu1_b + hproj[b])  (in-place, barrier-protected)
    k_mgemm<bf16,bf16><<<dim3(BL/128), dim3(256), 0, stream>>>(
        nh, glu1_w, 128, 0, glu1_b, 0, nh, 3, hproj, 2, nullptr);
    k_beta<<<dim3(BL/4), dim3(256), 0, stream>>>(betaB, nh, w_2);
    k_final<<<dim3(BATCH), dim3(128), 0, stream>>>(out, betaB, H1f, acc, uidx);
}

// Round 6
// 2329.248 us; speedup vs baseline: 10.4876x; 1.2249x over previous
//
#include <hip/hip_runtime.h>
#include <hip/hip_bf16.h>
#include <math.h>

typedef __hip_bfloat16 bf16;

__device__ __forceinline__ float b2f(bf16 x){ return __bfloat162float(x); }
__device__ __forceinline__ bf16  f2b(float x){ return __float2bfloat16(x); }

// raw-bits bf16 helpers (RNE, finite inputs)
__device__ __forceinline__ short f2bs(float f){
    unsigned u = __float_as_uint(f);
    u += 0x7fffu + ((u >> 16) & 1u);
    return (short)(u >> 16);
}
__device__ __forceinline__ float bs2f(short s){
    return __uint_as_float(((unsigned)(unsigned short)s) << 16);
}

#define NUSERS   10000
#define NPOIS    50000
#define SEQL     100
#define NNODES   60001
#define BATCH    1024
#define NNZG     1920000
#define NNZH     1600000
#define BL       (BATCH*SEQL)          // 102400
#define BLD      (BL*128)              // 13,107,200 elems
#define NND      (NNODES*128)          // 7,680,128
#define CN       (60000*128)           // 7,680,000
#define PD       (NPOIS*128)           // 6,400,000

__device__ __forceinline__ void  stc(bf16* p,  float v){ *p = f2b(v); }
__device__ __forceinline__ void  stc(float* p, float v){ *p = v; }

typedef __attribute__((ext_vector_type(8))) short s16x8;
typedef __attribute__((ext_vector_type(4))) float f32x4;

// ---------- zero-fill (16B granules) ----------
__global__ __launch_bounds__(256) void k_zero(float* __restrict__ p, int n4){
    int i = blockIdx.x*256 + threadIdx.x;
    if (i < n4) ((float4*)p)[i] = make_float4(0.f,0.f,0.f,0.f);
}

// ---------- 16B copy ----------
__global__ __launch_bounds__(256) void k_copy16(ulong2* __restrict__ dst,
                                                const ulong2* __restrict__ src, int n16){
    int i = blockIdx.x*256 + threadIdx.x;
    if (i < n16) dst[i] = src[i];
}

// ---------- init: nodes(bf16)=src, acc(f32)=src ----------
__global__ __launch_bounds__(256) void k_init(bf16* __restrict__ nodes, float* __restrict__ acc,
                                              const float* __restrict__ src, int n){
    int i = blockIdx.x*256 + threadIdx.x;
    if (i >= n) return;
    float v = src[i];
    nodes[i] = f2b(v); acc[i] = v;
}

// ---------- row gather f32 table -> f32 dst ----------
__global__ __launch_bounds__(256) void k_gather_f(float* __restrict__ dst,
                                                  const float* __restrict__ table,
                                                  const int* __restrict__ idx, int rows){
    int gid = blockIdx.x*256 + threadIdx.x;
    if (gid >= rows*128) return;
    int r = gid >> 7, c = gid & 127;
    dst[(size_t)r*128 + c] = table[(size_t)idx[r]*128 + c];
}

// ================= fused gather + geo + fc_geo + tot =================
// tot[b,l,c] = seq[b,l,c] + posl[l+1,c] + relu( (adj[b]@seq[b]) @ fcw^T + fcb )[l,c]
// seq[b,j,:] = nodes[seqs[b,j],:]  (gathered in-kernel)
__global__ __launch_bounds__(256) void k_mgeo2(bf16* __restrict__ tot,
                                               const bf16* __restrict__ nodes,
                                               const int* __restrict__ seqs,
                                               const float* __restrict__ adj,
                                               const float* __restrict__ fcw,
                                               const float* __restrict__ fcb,
                                               const float* __restrict__ posl){
    __shared__ short st[128*104];     // seq^T (col-major), pitch 104
    __shared__ short gt[112*136];     // geo tile bf16, pitch 136
    int b = blockIdx.x, tid = threadIdx.x;
    const int* sq = seqs + b*SEQL;
    for (int i = tid; i < SEQL*128; i += 256){
        int j = i >> 7, c = i & 127;
        st[c*104 + j] = ((const short*)nodes)[(size_t)sq[j]*128 + c];
    }
    for (int i = tid; i < 128*4; i += 256){ int c = i>>2, r = i&3; st[c*104 + 100 + r] = 0; }
    __syncthreads();
    int wv = tid>>6, lane = tid&63, lr = lane&15, lk = lane>>4;
    const s16x8 zf = {0,0,0,0,0,0,0,0};
    // phase-1 B-frags: wave's two 16-col tiles of seq^T
    s16x8 bfr[2][4];
    #pragma unroll
    for (int t = 0; t < 2; t++){
        int nt = wv*2 + t;
        #pragma unroll
        for (int kc = 0; kc < 4; kc++)
            bfr[t][kc] = *(const s16x8*)&st[(nt*16+lr)*104 + kc*32 + lk*8];
    }
    const float* ab = adj + (size_t)b*SEQL*SEQL;
    for (int mt = 0; mt < 7; mt++){
        int ar = min(mt*16 + lr, SEQL-1);          // clamp pad rows (discarded later)
        s16x8 ah[4], al[4];
        #pragma unroll
        for (int kc = 0; kc < 4; kc++){
            float av[8] = {0,0,0,0,0,0,0,0};
            if (kc < 3){
                const float* ap = ab + (size_t)ar*SEQL + kc*32 + lk*8;
                float4 a0 = *(const float4*)ap;
                float4 a1 = *(const float4*)(ap + 4);
                av[0]=a0.x; av[1]=a0.y; av[2]=a0.z; av[3]=a0.w;
                av[4]=a1.x; av[5]=a1.y; av[6]=a1.z; av[7]=a1.w;
            } else if (lk == 0){
                float4 a0 = *(const float4*)(ab + (size_t)ar*SEQL + 96);
                av[0]=a0.x; av[1]=a0.y; av[2]=a0.z; av[3]=a0.w;   // k=96..99
            }
            s16x8 h = zf, l = zf;
            #pragma unroll
            for (int j = 0; j < 8; j++){
                short hb = f2bs(av[j]);
                h[j] = hb;
                l[j] = f2bs(av[j] - bs2f(hb));
            }
            ah[kc] = h; al[kc] = l;
        }
        f32x4 c0 = {0.f,0.f,0.f,0.f}, c1 = {0.f,0.f,0.f,0.f};
        #pragma unroll
        for (int kc = 0; kc < 4; kc++){
            c0 = __builtin_amdgcn_mfma_f32_16x16x32_bf16(ah[kc], bfr[0][kc], c0, 0,0,0);
            c0 = __builtin_amdgcn_mfma_f32_16x16x32_bf16(al[kc], bfr[0][kc], c0, 0,0,0);
            c1 = __builtin_amdgcn_mfma_f32_16x16x32_bf16(ah[kc], bfr[1][kc], c1, 0,0,0);
            c1 = __builtin_amdgcn_mfma_f32_16x16x32_bf16(al[kc], bfr[1][kc], c1, 0,0,0);
        }
        #pragma unroll
        for (int t = 0; t < 2; t++){
            f32x4 cc = t ? c1 : c0;
            int col = wv*32 + t*16 + lr;
            #pragma unroll
            for (int r = 0; r < 4; r++){
                int row = mt*16 + lk*4 + r;          // store ALL rows incl. pad (finite)
                gt[row*136 + col] = f2bs(cc[r]);
            }
        }
    }
    // phase-2 W fragments (fc_geo_w, wstride=128)
    s16x8 wh[2][4], wl[2][4];
    int n0 = wv*32;
    #pragma unroll
    for (int t = 0; t < 2; t++){
        #pragma unroll
        for (int ks = 0; ks < 4; ks++){
            const float* wp = fcw + (size_t)(n0 + t*16 + lr)*128 + ks*32 + lk*8;
            float4 w0 = *(const float4*)(wp);
            float4 w1 = *(const float4*)(wp + 4);
            float wf[8] = {w0.x,w0.y,w0.z,w0.w,w1.x,w1.y,w1.z,w1.w};
            s16x8 h, l;
            #pragma unroll
            for (int j = 0; j < 8; j++){
                short hb = f2bs(wf[j]);
                h[j] = hb;
                l[j] = f2bs(wf[j] - bs2f(hb));
            }
            wh[t][ks] = h; wl[t][ks] = l;
        }
    }
    __syncthreads();
    for (int mt = 0; mt < 7; mt++){
        s16x8 ah[4];
        #pragma unroll
        for (int ks = 0; ks < 4; ks++)
            ah[ks] = *(const s16x8*)&gt[(mt*16+lr)*136 + ks*32 + lk*8];
        f32x4 c0 = {0.f,0.f,0.f,0.f}, c1 = {0.f,0.f,0.f,0.f};
        #pragma unroll
        for (int ks = 0; ks < 4; ks++){
            c0 = __builtin_amdgcn_mfma_f32_16x16x32_bf16(ah[ks], wh[0][ks], c0, 0,0,0);
            c0 = __builtin_amdgcn_mfma_f32_16x16x32_bf16(ah[ks], wl[0][ks], c0, 0,0,0);
            c1 = __builtin_amdgcn_mfma_f32_16x16x32_bf16(ah[ks], wh[1][ks], c1, 0,0,0);
            c1 = __builtin_amdgcn_mfma_f32_16x16x32_bf16(ah[ks], wl[1][ks], c1, 0,0,0);
        }
        #pragma unroll
        for (int t = 0; t < 2; t++){
            f32x4 cc = t ? c1 : c0;
            int col = n0 + t*16 + lr;
            float bv = fcb[col];
            #pragma unroll
            for (int r = 0; r < 4; r++){
                int row = mt*16 + lk*4 + r;
                if (row < SEQL){
                    float v = fmaxf(cc[r] + bv, 0.f);
                    v += bs2f(st[col*104 + row]) + posl[(row+1)*128 + col];
                    tot[(size_t)b*SEQL*128 + (size_t)row*128 + col] = f2b(v);
                }
            }
        }
    }
}

// ================= MFMA GEMM =================
// C[M,128] = epilogue( A[M,128] @ W[n, wstride; +woff]^T )
// W f32 -> bf16 hi+lo in-register. TA=bf16: 2 terms; TA=float: 3 terms.
// act: 0=none 1=relu 2=tanh 3=sigmoid
// addmode 1: += add1[((m%SEQL)+1)*masks[m]*128+n]; 2: += add1[(m/SEQL)*128+n]
// In-place safe via per-stripe __syncthreads.
template<typename TA, typename TC>
__global__ __launch_bounds__(256) void k_mgemm(const TA* __restrict__ A,
                                               const float* __restrict__ W, int wstride, int woff,
                                               const float* __restrict__ bias, int boff,
                                               TC* __restrict__ C, int act,
                                               const float* __restrict__ add1, int addmode,
                                               const int* __restrict__ masks){
    constexpr bool A_BF = (sizeof(TA) == 2);
    int tid  = threadIdx.x;
    int wv   = tid >> 6;
    int lane = tid & 63;
    int lr   = lane & 15;
    int lk   = lane >> 4;
    int n0   = wv * 32;

    s16x8 wh[2][4], wl[2][4];
    #pragma unroll
    for (int t = 0; t < 2; t++){
        #pragma unroll
        for (int ks = 0; ks < 4; ks++){
            const float* wp = W + (size_t)(n0 + t*16 + lr)*wstride + woff + ks*32 + lk*8;
            float4 w0 = *(const float4*)(wp);
            float4 w1 = *(const float4*)(wp + 4);
            float wf[8] = {w0.x,w0.y,w0.z,w0.w,w1.x,w1.y,w1.z,w1.w};
            s16x8 h, l;
            #pragma unroll
            for (int j = 0; j < 8; j++){
                short hb = f2bs(wf[j]);
                h[j] = hb;
                l[j] = f2bs(wf[j] - bs2f(hb));
            }
            wh[t][ks] = h; wl[t][ks] = l;
        }
    }

    size_t mblk = (size_t)blockIdx.x * 128;
    for (int it = 0; it < 8; it++){
        size_t m0 = mblk + (size_t)it*16;
        s16x8 ah[4], al[4];
        #pragma unroll
        for (int ks = 0; ks < 4; ks++){
            if constexpr (A_BF){
                ah[ks] = *(const s16x8*)((const short*)A + (m0 + lr)*128 + ks*32 + lk*8);
            } else {
                const float* ap = (const float*)A + (m0 + lr)*128 + ks*32 + lk*8;
                float4 a0 = *(const float4*)(ap);
                float4 a1 = *(const float4*)(ap + 4);
                float av[8] = {a0.x,a0.y,a0.z,a0.w,a1.x,a1.y,a1.z,a1.w};
                s16x8 h, l;
                #pragma unroll
                for (int j = 0; j < 8; j++){
                    short hb = f2bs(av[j]);
                    h[j] = hb;
                    l[j] = f2bs(av[j] - bs2f(hb));
                }
                ah[ks] = h; al[ks] = l;
            }
        }
        __syncthreads();   // in-place safety: all reads of stripe before any writes
        f32x4 c0 = {0.f,0.f,0.f,0.f}, c1 = {0.f,0.f,0.f,0.f};
        #pragma unroll
        for (int ks = 0; ks < 4; ks++){
            c0 = __builtin_amdgcn_mfma_f32_16x16x32_bf16(ah[ks], wh[0][ks], c0, 0, 0, 0);
            c0 = __builtin_amdgcn_mfma_f32_16x16x32_bf16(ah[ks], wl[0][ks], c0, 0, 0, 0);
            c1 = __builtin_amdgcn_mfma_f32_16x16x32_bf16(ah[ks], wh[1][ks], c1, 0, 0, 0);
            c1 = __builtin_amdgcn_mfma_f32_16x16x32_bf16(ah[ks], wl[1][ks], c1, 0, 0, 0);
            if constexpr (!A_BF){
                c0 = __builtin_amdgcn_mfma_f32_16x16x32_bf16(al[ks], wh[0][ks], c0, 0, 0, 0);
                c1 = __builtin_amdgcn_mfma_f32_16x16x32_bf16(al[ks], wh[1][ks], c1, 0, 0, 0);
            }
        }
        #pragma unroll
        for (int t = 0; t < 2; t++){
            f32x4 cc = t ? c1 : c0;
            int c = n0 + t*16 + lr;
            float bv = bias ? bias[boff + c] : 0.f;
            #pragma unroll
            for (int r4 = 0; r4 < 4; r4++){
                int m = (int)m0 + lk*4 + r4;
                float v = cc[r4] + bv;
                if (addmode == 1){
                    int l = m % SEQL;
                    int p = (l+1) * masks[m];
                    v += add1[p*128 + c];
                } else if (addmode == 2){
                    v += add1[(m/SEQL)*128 + c];
                }
                if (act == 1) v = fmaxf(v, 0.f);
                else if (act == 2) v = tanhf(v);
                else if (act == 3) v = 1.f/(1.f+__expf(-v));
                stc(&C[(size_t)m*128 + c], v);
            }
        }
    }
}

// ================= MFMA attention =================
// One block per b; 4 waves x 2 heads. d_head=16 -> K=32 MFMA with upper half zero.
// Softmax wave-parallel (quarter shfl reductions). P stored bf16 hi+lo (precision).
// O aliases Q's plane: each wave touches only its own heads' columns.
// NOTE: no __restrict__ (o/Qq alias). Pad rows clamped to stay in-bounds.
__global__ __launch_bounds__(256) void k_mattn(bf16* o, const bf16* Qq,
                                               const bf16* Qk, const bf16* Qv){
    __shared__ short Vt[128*104];      // V^T, pitch 104
    __shared__ short Ph[4][16*136];    // per-wave P stripe (hi), pitch 136
    __shared__ short Pl[4][16*136];    // per-wave P stripe (lo)
    int b = blockIdx.x, tid = threadIdx.x;
    const short* vsrc = (const short*)(Qv + (size_t)b*SEQL*128);
    for (int i = tid; i < SEQL*128; i += 256){ int j = i>>7, c = i&127; Vt[c*104 + j] = vsrc[i]; }
    for (int i = tid; i < 128*4; i += 256){ int c = i>>2, r = i&3; Vt[c*104 + 100 + r] = 0; }
    int wv = tid>>6, lane = tid&63, lr = lane&15, lk = lane>>4;
    short* phw = Ph[wv];
    short* plw = Pl[wv];
    for (int i = lane; i < 16*136; i += 64){ phw[i] = 0; plw[i] = 0; }
    __syncthreads();

    const s16x8 zf = {0,0,0,0,0,0,0,0};
    size_t rowbase = (size_t)b*SEQL*128;
    bool kreal = (lk < 2);
    for (int hh = 0; hh < 2; hh++){
        int h = wv*2 + hh;
        int hd = h*16 + lk*8;
        s16x8 kf[7];
        #pragma unroll
        for (int nt = 0; nt < 7; nt++){
            int kr = min(nt*16 + lr, SEQL-1);
            kf[nt] = kreal ? *(const s16x8*)((const short*)Qk + rowbase + (size_t)kr*128 + hd) : zf;
        }
        s16x8 vf[4];
        #pragma unroll
        for (int kc = 0; kc < 4; kc++)
            vf[kc] = *(const s16x8*)&Vt[(h*16+lr)*104 + kc*32 + lk*8];

        for (int mt = 0; mt < 7; mt++){
            int qr = min(mt*16 + lr, SEQL-1);
            s16x8 qf = kreal ? *(const s16x8*)((const short*)Qq + rowbase + (size_t)qr*128 + hd) : zf;
            f32x4 sc[7];
            #pragma unroll
            for (int nt = 0; nt < 7; nt++){
                f32x4 z = {0.f,0.f,0.f,0.f};
                sc[nt] = __builtin_amdgcn_mfma_f32_16x16x32_bf16(qf, kf[nt], z, 0,0,0);
            }
            float mx[4] = {-1e30f,-1e30f,-1e30f,-1e30f};
            #pragma unroll
            for (int nt = 0; nt < 7; nt++){
                bool masked = (nt == 6) && (lr >= 4);   // cols >= 100
                #pragma unroll
                for (int r = 0; r < 4; r++){
                    float s = masked ? -1e30f : sc[nt][r]*0.25f;
                    sc[nt][r] = s;
                    mx[r] = fmaxf(mx[r], s);
                }
            }
            #pragma unroll
            for (int m = 1; m < 16; m <<= 1){
                #pragma unroll
                for (int r = 0; r < 4; r++) mx[r] = fmaxf(mx[r], __shfl_xor(mx[r], m));
            }
            float sm[4] = {0.f,0.f,0.f,0.f};
            #pragma unroll
            for (int nt = 0; nt < 7; nt++){
                #pragma unroll
                for (int r = 0; r < 4; r++){
                    float p = __expf(sc[nt][r] - mx[r]);
                    sc[nt][r] = p; sm[r] += p;
                }
            }
            #pragma unroll
            for (int m = 1; m < 16; m <<= 1){
                #pragma unroll
                for (int r = 0; r < 4; r++) sm[r] += __shfl_xor(sm[r], m);
            }
            float inv[4];
            #pragma unroll
            for (int r = 0; r < 4; r++) inv[r] = 1.f/sm[r];
            #pragma unroll
            for (int nt = 0; nt < 7; nt++){
                #pragma unroll
                for (int r = 0; r < 4; r++){
                    float p = sc[nt][r]*inv[r];
                    short hb = f2bs(p);
                    int pa = (lk*4+r)*136 + nt*16 + lr;
                    phw[pa] = hb;
                    plw[pa] = f2bs(p - bs2f(hb));
                }
            }
            f32x4 oa = {0.f,0.f,0.f,0.f};
            #pragma unroll
            for (int kc = 0; kc < 4; kc++){
                s16x8 pah = *(const s16x8*)&phw[lr*136 + kc*32 + lk*8];
                s16x8 pal = *(const s16x8*)&plw[lr*136 + kc*32 + lk*8];
                oa = __builtin_amdgcn_mfma_f32_16x16x32_bf16(pah, vf[kc], oa, 0,0,0);
                oa = __builtin_amdgcn_mfma_f32_16x16x32_bf16(pal, vf[kc], oa, 0,0,0);
            }
            #pragma unroll
            for (int r = 0; r < 4; r++){
                int row = mt*16 + lk*4 + r;
                if (row < SEQL)
                    ((short*)o)[rowbase + (size_t)row*128 + h*16 + lr] = f2bs(oa[r]);
            }
        }
    }
}

// ---------- users = mean_l(o2) -> nodes[uidx[b]] ----------
__global__ __launch_bounds__(128) void k_mean_users(bf16* __restrict__ nodes,
                                                    const bf16* __restrict__ o,
                                                    const int* __restrict__ uidx){
    int b = blockIdx.x, c = threadIdx.x;
    const bf16* p = o + (size_t)b*SEQL*128 + c;
    float sum = 0.f;
    for (int l = 0; l < SEQL; l++) sum += b2f(p[l*128]);
    nodes[(size_t)uidx[b]*128 + c] = f2b(sum * (1.f/(float)SEQL));
}

// ================= CSR build + row-wave SpMM =================

__global__ __launch_bounds__(256) void k_hist(int* __restrict__ cnt,
                                              const int* __restrict__ rows, int nnz){
    int e = blockIdx.x*256 + threadIdx.x;
    if (e < nnz) atomicAdd(&cnt[rows[e]], 1);
}

__global__ __launch_bounds__(1024) void k_scan(int* __restrict__ cnt,
                                               int* __restrict__ rowptr, int nrows){
    __shared__ int part[1024];
    int tid = threadIdx.x;
    int chunk = (nrows + 1023) >> 10;
    int s = tid*chunk, e = min(s+chunk, nrows);
    int sum = 0;
    for (int i = s; i < e; i++) sum += cnt[i];
    part[tid] = sum;
    __syncthreads();
    for (int off = 1; off < 1024; off <<= 1){
        int add = (tid >= off) ? part[tid-off] : 0;
        __syncthreads();
        part[tid] += add;
        __syncthreads();
    }
    int run = part[tid] - sum;
    for (int i = s; i < e; i++){
        int c = cnt[i];
        rowptr[i] = run;
        cnt[i]    = run;
        run += c;
    }
    if (tid == 0) rowptr[nrows] = part[1023];
}

__global__ __launch_bounds__(256) void k_scatter(int2* __restrict__ cv,
                                                 int* __restrict__ cur,
                                                 const int* __restrict__ rows,
                                                 const int* __restrict__ cols,
                                                 const float* __restrict__ vals, int nnz){
    int e = blockIdx.x*256 + threadIdx.x;
    if (e >= nnz) return;
    int p = atomicAdd(&cur[rows[e]], 1);
    cv[p] = make_int2(cols[e], __float_as_int(vals[e]));
}

// one wave per row, 4 edge-slots x 16 lanes; lane loads 16B (8 bf16) of x-row.
// Writes result row to yb (bf16) and acc += (single writer per row).
// x must be a SNAPSHOT distinct from yb.
__global__ __launch_bounds__(256) void k_spmm_csr(bf16* __restrict__ yb,
                                                  float* __restrict__ acc,
                                                  const int* __restrict__ rowptr,
                                                  const int2* __restrict__ cv,
                                                  const bf16* __restrict__ x, int nrows){
    int row = blockIdx.x*4 + (threadIdx.x >> 6);
    if (row >= nrows) return;
    int lane = threadIdx.x & 63;
    int g = lane >> 4;           // edge-slot 0..3
    int t = lane & 15;           // col-group: cols t*8 .. t*8+7
    int s = rowptr[row], e = rowptr[row+1];
    float a[8] = {0.f,0.f,0.f,0.f,0.f,0.f,0.f,0.f};
    for (int i = s + g; i < e; i += 4){
        int2 p = cv[i];
        float v = __int_as_float(p.y);
        uint4 u = *(const uint4*)(x + (size_t)p.x*128 + t*8);
        unsigned w0 = u.x, w1 = u.y, w2 = u.z, w3 = u.w;
        a[0] += v * __uint_as_float((w0 & 0xffffu) << 16);
        a[1] += v * __uint_as_float(w0 & 0xffff0000u);
        a[2] += v * __uint_as_float((w1 & 0xffffu) << 16);
        a[3] += v * __uint_as_float(w1 & 0xffff0000u);
        a[4] += v * __uint_as_float((w2 & 0xffffu) << 16);
        a[5] += v * __uint_as_float(w2 & 0xffff0000u);
        a[6] += v * __uint_as_float((w3 & 0xffffu) << 16);
        a[7] += v * __uint_as_float(w3 & 0xffff0000u);
    }
    #pragma unroll
    for (int j = 0; j < 8; j++){
        a[j] += __shfl_xor(a[j], 16);
        a[j] += __shfl_xor(a[j], 32);
    }
    if (g == 0){
        s16x8 ob;
        #pragma unroll
        for (int j = 0; j < 8; j++) ob[j] = f2bs(a[j]);
        *(s16x8*)((short*)yb + (size_t)row*128 + t*8) = ob;
        float* ap = acc + (size_t)row*128 + t*8;
        float4 c0 = ((float4*)ap)[0], c1 = ((float4*)ap)[1];
        c0.x += a[0]; c0.y += a[1]; c0.z += a[2]; c0.w += a[3];
        c1.x += a[4]; c1.y += a[5]; c1.z += a[6]; c1.w += a[7];
        ((float4*)ap)[0] = c0; ((float4*)ap)[1] = c1;
    }
}

__global__ __launch_bounds__(256) void k_scale(float* __restrict__ a, int n){
    int i = blockIdx.x*256 + threadIdx.x;
    if (i < n) a[i] *= (1.f/3.f);
}

// ---------- global branch init ----------
__global__ __launch_bounds__(256) void k_initg(bf16* __restrict__ xg, float* __restrict__ accg,
                                               const float* __restrict__ ne, int n){
    int i = blockIdx.x*256 + threadIdx.x;
    if (i >= n) return;
    float v = ne[(size_t)NUSERS*128 + i];
    xg[i] = f2b(v); accg[i] = v;
}

// ---------- fusion: acc_poi += accg/3; emit pois output (f32!) ----------
__global__ __launch_bounds__(256) void k_fusion(float* __restrict__ accP,
                                                const float* __restrict__ accg,
                                                float* __restrict__ outp, int n){
    int i = blockIdx.x*256 + threadIdx.x;
    if (i >= n) return;
    float v = accP[i] + accg[i]*(1.f/3.f);
    accP[i] = v;
    outp[i] = v;
}

// ================= HEAD =================

__global__ __launch_bounds__(128) void k_hs(float* __restrict__ hs, const float* __restrict__ sh,
                                            const float* __restrict__ lens){
    int b = blockIdx.x, c = threadIdx.x;
    const float* p = sh + (size_t)b*SEQL*128 + c;
    float sum = 0.f;
    for (int l = 0; l < SEQL; l++) sum += p[l*128];
    hs[b*128 + c] = sum / lens[b];
}

__global__ __launch_bounds__(128) void k_posw(float* __restrict__ posW,
                                              const float* __restrict__ pg,
                                              const float* __restrict__ w1w){
    __shared__ float sm[128];
    int p = blockIdx.x, n = threadIdx.x;
    sm[n] = pg[p*128 + n];
    __syncthreads();
    const float* wr = w1w + (size_t)n*256;
    float s = 0.f;
    for (int k = 0; k < 128; k++) s += sm[k]*wr[k];
    posW[p*128 + n] = s;
}

// ---------- beta: per-wave reduction, 4 rows/block ----------
__global__ __launch_bounds__(256) void k_beta(float* __restrict__ beta,
                                              const bf16* __restrict__ nh,
                                              const float* __restrict__ w2){
    int m = blockIdx.x*4 + (threadIdx.x >> 6);
    int lane = threadIdx.x & 63;
    float v = b2f(nh[(size_t)m*128 + lane]) * w2[lane]
            + b2f(nh[(size_t)m*128 + 64 + lane]) * w2[64 + lane];
    #pragma unroll
    for (int s = 1; s < 64; s <<= 1) v += __shfl_xor(v, s);
    if (lane == 0) beta[m] = v;
}

__global__ __launch_bounds__(128) void k_final(float* __restrict__ out,
                                               const float* __restrict__ beta,
                                               const float* __restrict__ seqh,
                                               const float* __restrict__ acc,
                                               const int* __restrict__ uidx){
    int b = blockIdx.x, c = threadIdx.x;
    const float* sh = seqh + (size_t)b*SEQL*128 + c;
    const float* bp = beta + b*SEQL;
    float sel = 0.f;
    for (int l = 0; l < SEQL; l++) sel += bp[l]*sh[l*128];
    out[b*128 + c] = sel + acc[(size_t)uidx[b]*128 + c];
}

extern "C" void kernel_launch(void* const* d_in, const int* in_sizes, int n_in,
                              void* d_out, int out_size, void* d_ws, size_t ws_size,
                              hipStream_t stream){
    const float* nodes_emb     = (const float*)d_in[0];
    const float* pos_emb_local = (const float*)d_in[1];
    const float* fc_geo_w      = (const float*)d_in[2];
    const float* fc_geo_b      = (const float*)d_in[3];
    const float* in_proj_w     = (const float*)d_in[4];
    const float* in_proj_b     = (const float*)d_in[5];
    const float* out_proj_w    = (const float*)d_in[6];
    const float* out_proj_b    = (const float*)d_in[7];
    const float* pos_emb_glob  = (const float*)d_in[8];
    const float* w1_w          = (const float*)d_in[9];
    const float* w1_b          = (const float*)d_in[10];
    const float* w_2           = (const float*)d_in[11];
    const float* glu1_w        = (const float*)d_in[12];
    const float* glu1_b        = (const float*)d_in[13];
    const float* glu2_w        = (const float*)d_in[14];
    const int*   G_rows        = (const int*)d_in[15];
    const int*   G_cols        = (const int*)d_in[16];
    const float* G_vals        = (const float*)d_in[17];
    const int*   HG_rows       = (const int*)d_in[18];
    const int*   HG_cols       = (const int*)d_in[19];
    const float* HG_vals       = (const float*)d_in[20];
    const int*   seqs          = (const int*)d_in[21];
    const int*   masks         = (const int*)d_in[22];
    const float* adjs          = (const float*)d_in[23];
    const int*   uidx          = (const int*)d_in[24];
    const float* lens          = (const float*)d_in[25];
    const int*   rev_seqs      = (const int*)d_in[26];
    float* out = (float*)d_out;   // OUTPUT IS FLOAT32

    // ---- workspace layout; max offset used = 124,723,968 B ----
    char* base = (char*)d_ws;
    bf16*  nodes = (bf16*)base;                               // [0, 15,360,256)
    float* acc   = (float*)(base + 15360256);                 // [.., 46,080,768)
    char*  R     = base + 15360256 + 30720512;                // [46,080,768, 124,723,968)
    // layer-phase aliases inside R:
    bf16* P1 = (bf16*)R;          // BLD bf16
    bf16* P2 = P1 + BLD;
    bf16* P3 = P2 + BLD;
    // spmm-window aliases (P1/P2/P3 dead):
    bf16*  xsnap = (bf16*)R;                         // 60000-row bf16 snapshot (15.36 MB)
    int2*  Gcv  = (int2*)(R + 30720000);             // NNZG*8 -> ends 46,080,000
    int*   Gptr = (int*)(R + 46080000);              // 60001*4
    int*   Gcur = (int*)(R + 46320016);              // 60000*4 (16B aligned)
    // global-phase aliases:
    bf16*  xg     = (bf16*)R;                        // PD bf16
    bf16*  xsnapg = (bf16*)(R + 12800000);           // PD bf16 snapshot
    float* accg = (float*)(R + 12800000 + 25600000); // PD f32 -> ends 64,000,000
    int2*  Hcv  = (int2*)(R + 64000000);             // NNZH*8 -> ends 76,800,000
    int*   Hptr = (int*)(R + 76800000);              // 50001*4
    int*   Hcur = (int*)(R + 77000016);              // 50000*4 (16B aligned)
    // head-phase aliases:
    float* H1f  = (float*)R;                         // BLD f32
    bf16*  nh   = (bf16*)(R + 52428800);             // BLD bf16 -> ends 78,643,200
    float* hs    = (float*)base;                     // small bufs in dead nodes region
    float* hproj = (float*)(base + 524288);
    float* posW  = (float*)(base + 1048576);
    float* betaB = (float*)(base + 1100288);

    auto gemm = [&](const bf16* A, const float* W, int wstride, int woff,
                    const float* bias, int boff, bf16* Cp, int act){
        k_mgemm<bf16,bf16><<<dim3(BL/128), dim3(256), 0, stream>>>(
            A, W, wstride, woff, bias, boff, Cp, act, nullptr, 0, nullptr);
    };

    // init: nodes (bf16) = nodes_emb, acc (f32) = nodes_emb
    k_init<<<dim3((NND+255)/256), dim3(256), 0, stream>>>(nodes, acc, nodes_emb, NND);

    for (int layer = 0; layer < 2; layer++){
        // fused gather + geo + fc_geo + tot -> P3
        k_mgeo2<<<dim3(BATCH), dim3(256), 0, stream>>>(P3, nodes, seqs, adjs,
                                                       fc_geo_w, fc_geo_b, pos_emb_local);
        gemm(P3, in_proj_w, 128, 0,       in_proj_b, 0,   P1, 0); // Q
        gemm(P3, in_proj_w, 128, 128*128, in_proj_b, 128, P2, 0); // K
        gemm(P3, in_proj_w, 128, 256*128, in_proj_b, 256, P3, 0); // V in-place
        k_mattn<<<dim3(BATCH), dim3(256), 0, stream>>>(P1, P1, P2, P3);   // O over Q
        gemm(P1, out_proj_w, 128, 0, out_proj_b, 0, P2, 0);
        k_mean_users<<<dim3(BATCH), dim3(128), 0, stream>>>(nodes, P2, uidx);
        // ---- build G CSR (scratch in dead P2/P3 space; rebuilt each layer) ----
        k_zero<<<dim3((15000+255)/256), dim3(256), 0, stream>>>((float*)Gcur, 15000); // 60000 ints
        k_hist<<<dim3(NNZG/256), dim3(256), 0, stream>>>(Gcur, G_rows, NNZG);
        k_scan<<<dim3(1), dim3(1024), 0, stream>>>(Gcur, Gptr, 60000);
        k_scatter<<<dim3(NNZG/256), dim3(256), 0, stream>>>(Gcv, Gcur, G_rows, G_cols, G_vals, NNZG);
        // snapshot x, then SpMM writes nodes (bf16) + acc += directly
        k_copy16<<<dim3((960000+255)/256), dim3(256), 0, stream>>>(
            (ulong2*)xsnap, (const ulong2*)nodes, 960000);
        k_spmm_csr<<<dim3(60000/4), dim3(256), 0, stream>>>(nodes, acc, Gptr, Gcv, xsnap, 60000);
    }
    // local = acc/3
    k_scale<<<dim3((NND+255)/256), dim3(256), 0, stream>>>(acc, NND);

    // global hypergraph branch
    k_initg<<<dim3((PD+255)/256), dim3(256), 0, stream>>>(xg, accg, nodes_emb, PD);
    k_zero<<<dim3((12500+255)/256), dim3(256), 0, stream>>>((float*)Hcur, 12500); // 50000 ints
    k_hist<<<dim3(NNZH/256), dim3(256), 0, stream>>>(Hcur, HG_rows, NNZH);
    k_scan<<<dim3(1), dim3(1024), 0, stream>>>(Hcur, Hptr, 50000);
    k_scatter<<<dim3(NNZH/256), dim3(256), 0, stream>>>(Hcv, Hcur, HG_rows, HG_cols, HG_vals, NNZH);
    for (int it = 0; it < 2; it++){
        k_copy16<<<dim3((800000+255)/256), dim3(256), 0, stream>>>(
            (ulong2*)xsnapg, (const ulong2*)xg, 800000);
        k_spmm_csr<<<dim3(50000/4), dim3(256), 0, stream>>>(xg, accg, Hptr, Hcv, xsnapg, 50000);
    }
    // fusion: pois rows of acc += accg/3, emit pois output (f32, offset in f32 elems)
    k_fusion<<<dim3((PD+255)/256), dim3(256), 0, stream>>>(acc + (size_t)NUSERS*128, accg, out + BATCH*128, PD);

    // ===== head (f32 path) =====
    k_gather_f<<<dim3((BL*128+255)/256), dim3(256), 0, stream>>>(H1f, acc, rev_seqs, BL);
    k_hs<<<dim3(BATCH), dim3(128), 0, stream>>>(hs, H1f, lens);
    // hproj = hs @ glu2_w^T  (f32-A 3-term MFMA path)
    k_mgemm<float,float><<<dim3(BATCH/128), dim3(256), 0, stream>>>(
        hs, glu2_w, 128, 0, nullptr, 0, hproj, 0, nullptr, 0, nullptr);
    k_posw<<<dim3(SEQL+1), dim3(128), 0, stream>>>(posW, pos_emb_glob, w1_w);
    // nh1 = tanh(H1f @ w1_w[:,128:]^T + posW[pidx] + w1_b)
    k_mgemm<float,bf16><<<dim3(BL/128), dim3(256), 0, stream>>>(
        H1f, w1_w, 256, 128, w1_b, 0, nh, 2, posW, 1, masks);
    // nh2 = sigmoid(nh @ glu1_w^T + glu1_b + hproj[b])  (in-place, barrier-protected)
    k_mgemm<bf16,bf16><<<dim3(BL/128), dim3(256), 0, stream>>>(
        nh, glu1_w, 128, 0, glu1_b, 0, nh, 3, hproj, 2, nullptr);
    k_beta<<<dim3(BL/4), dim3(256), 0, stream>>>(betaB, nh, w_2);
    k_final<<<dim3(BATCH), dim3(128), 0, stream>>>(out, betaB, H1f, acc, uidx);
}

// Round 7
// 1967.907 us; speedup vs baseline: 12.4132x; 1.1836x over previous
//
#include <hip/hip_runtime.h>
#include <hip/hip_bf16.h>
#include <math.h>

typedef __hip_bfloat16 bf16;

__device__ __forceinline__ float b2f(bf16 x){ return __bfloat162float(x); }
__device__ __forceinline__ bf16  f2b(float x){ return __float2bfloat16(x); }

// raw-bits bf16 helpers (RNE, finite inputs)
__device__ __forceinline__ short f2bs(float f){
    unsigned u = __float_as_uint(f);
    u += 0x7fffu + ((u >> 16) & 1u);
    return (short)(u >> 16);
}
__device__ __forceinline__ float bs2f(short s){
    return __uint_as_float(((unsigned)(unsigned short)s) << 16);
}

#define NUSERS   10000
#define NPOIS    50000
#define SEQL     100
#define NNODES   60001
#define BATCH    1024
#define NNZG     1920000
#define NNZH     1600000
#define BL       (BATCH*SEQL)          // 102400
#define BLD      (BL*128)              // 13,107,200 elems
#define NND      (NNODES*128)          // 7,680,128
#define CN       (60000*128)           // 7,680,000
#define PD       (NPOIS*128)           // 6,400,000

__device__ __forceinline__ void  stc(bf16* p,  float v){ *p = f2b(v); }
__device__ __forceinline__ void  stc(float* p, float v){ *p = v; }

typedef __attribute__((ext_vector_type(8))) short s16x8;
typedef __attribute__((ext_vector_type(4))) float f32x4;

// ---------- zero-fill (16B granules) ----------
__global__ __launch_bounds__(256) void k_zero(float* __restrict__ p, int n4){
    int i = blockIdx.x*256 + threadIdx.x;
    if (i < n4) ((float4*)p)[i] = make_float4(0.f,0.f,0.f,0.f);
}

// ---------- 16B copy ----------
__global__ __launch_bounds__(256) void k_copy16(ulong2* __restrict__ dst,
                                                const ulong2* __restrict__ src, int n16){
    int i = blockIdx.x*256 + threadIdx.x;
    if (i < n16) dst[i] = src[i];
}

// ---------- init: nodes(bf16)=src, acc(f32)=src ----------
__global__ __launch_bounds__(256) void k_init(bf16* __restrict__ nodes, float* __restrict__ acc,
                                              const float* __restrict__ src, int n){
    int i = blockIdx.x*256 + threadIdx.x;
    if (i >= n) return;
    float v = src[i];
    nodes[i] = f2b(v); acc[i] = v;
}

// ---------- row gather f32 table -> f32 dst ----------
__global__ __launch_bounds__(256) void k_gather_f(float* __restrict__ dst,
                                                  const float* __restrict__ table,
                                                  const int* __restrict__ idx, int rows){
    int gid = blockIdx.x*256 + threadIdx.x;
    if (gid >= rows*128) return;
    int r = gid >> 7, c = gid & 127;
    dst[(size_t)r*128 + c] = table[(size_t)idx[r]*128 + c];
}

// ================= fused gather + geo + fc_geo + tot =================
// tot[b,l,c] = seq[b,l,c] + posl[l+1,c] + relu( (adj[b]@seq[b]) @ fcw^T + fcb )[l,c]
// seq[b,j,:] = nodes[seqs[b,j],:]  (gathered in-kernel)
__global__ __launch_bounds__(256) void k_mgeo2(bf16* __restrict__ tot,
                                               const bf16* __restrict__ nodes,
                                               const int* __restrict__ seqs,
                                               const float* __restrict__ adj,
                                               const float* __restrict__ fcw,
                                               const float* __restrict__ fcb,
                                               const float* __restrict__ posl){
    __shared__ short st[128*104];     // seq^T (col-major), pitch 104
    __shared__ short gt[112*136];     // geo tile bf16, pitch 136
    int b = blockIdx.x, tid = threadIdx.x;
    const int* sq = seqs + b*SEQL;
    for (int i = tid; i < SEQL*128; i += 256){
        int j = i >> 7, c = i & 127;
        st[c*104 + j] = ((const short*)nodes)[(size_t)sq[j]*128 + c];
    }
    for (int i = tid; i < 128*4; i += 256){ int c = i>>2, r = i&3; st[c*104 + 100 + r] = 0; }
    __syncthreads();
    int wv = tid>>6, lane = tid&63, lr = lane&15, lk = lane>>4;
    const s16x8 zf = {0,0,0,0,0,0,0,0};
    s16x8 bfr[2][4];
    #pragma unroll
    for (int t = 0; t < 2; t++){
        int nt = wv*2 + t;
        #pragma unroll
        for (int kc = 0; kc < 4; kc++)
            bfr[t][kc] = *(const s16x8*)&st[(nt*16+lr)*104 + kc*32 + lk*8];
    }
    const float* ab = adj + (size_t)b*SEQL*SEQL;
    for (int mt = 0; mt < 7; mt++){
        int ar = min(mt*16 + lr, SEQL-1);          // clamp pad rows (discarded later)
        s16x8 ah[4], al[4];
        #pragma unroll
        for (int kc = 0; kc < 4; kc++){
            float av[8] = {0,0,0,0,0,0,0,0};
            if (kc < 3){
                const float* ap = ab + (size_t)ar*SEQL + kc*32 + lk*8;
                float4 a0 = *(const float4*)ap;
                float4 a1 = *(const float4*)(ap + 4);
                av[0]=a0.x; av[1]=a0.y; av[2]=a0.z; av[3]=a0.w;
                av[4]=a1.x; av[5]=a1.y; av[6]=a1.z; av[7]=a1.w;
            } else if (lk == 0){
                float4 a0 = *(const float4*)(ab + (size_t)ar*SEQL + 96);
                av[0]=a0.x; av[1]=a0.y; av[2]=a0.z; av[3]=a0.w;   // k=96..99
            }
            s16x8 h = zf, l = zf;
            #pragma unroll
            for (int j = 0; j < 8; j++){
                short hb = f2bs(av[j]);
                h[j] = hb;
                l[j] = f2bs(av[j] - bs2f(hb));
            }
            ah[kc] = h; al[kc] = l;
        }
        f32x4 c0 = {0.f,0.f,0.f,0.f}, c1 = {0.f,0.f,0.f,0.f};
        #pragma unroll
        for (int kc = 0; kc < 4; kc++){
            c0 = __builtin_amdgcn_mfma_f32_16x16x32_bf16(ah[kc], bfr[0][kc], c0, 0,0,0);
            c0 = __builtin_amdgcn_mfma_f32_16x16x32_bf16(al[kc], bfr[0][kc], c0, 0,0,0);
            c1 = __builtin_amdgcn_mfma_f32_16x16x32_bf16(ah[kc], bfr[1][kc], c1, 0,0,0);
            c1 = __builtin_amdgcn_mfma_f32_16x16x32_bf16(al[kc], bfr[1][kc], c1, 0,0,0);
        }
        #pragma unroll
        for (int t = 0; t < 2; t++){
            f32x4 cc = t ? c1 : c0;
            int col = wv*32 + t*16 + lr;
            #pragma unroll
            for (int r = 0; r < 4; r++){
                int row = mt*16 + lk*4 + r;          // store ALL rows incl. pad (finite)
                gt[row*136 + col] = f2bs(cc[r]);
            }
        }
    }
    // phase-2 W fragments (fc_geo_w, wstride=128)
    s16x8 wh[2][4], wl[2][4];
    int n0 = wv*32;
    #pragma unroll
    for (int t = 0; t < 2; t++){
        #pragma unroll
        for (int ks = 0; ks < 4; ks++){
            const float* wp = fcw + (size_t)(n0 + t*16 + lr)*128 + ks*32 + lk*8;
            float4 w0 = *(const float4*)(wp);
            float4 w1 = *(const float4*)(wp + 4);
            float wf[8] = {w0.x,w0.y,w0.z,w0.w,w1.x,w1.y,w1.z,w1.w};
            s16x8 h, l;
            #pragma unroll
            for (int j = 0; j < 8; j++){
                short hb = f2bs(wf[j]);
                h[j] = hb;
                l[j] = f2bs(wf[j] - bs2f(hb));
            }
            wh[t][ks] = h; wl[t][ks] = l;
        }
    }
    __syncthreads();
    for (int mt = 0; mt < 7; mt++){
        s16x8 ah[4];
        #pragma unroll
        for (int ks = 0; ks < 4; ks++)
            ah[ks] = *(const s16x8*)&gt[(mt*16+lr)*136 + ks*32 + lk*8];
        f32x4 c0 = {0.f,0.f,0.f,0.f}, c1 = {0.f,0.f,0.f,0.f};
        #pragma unroll
        for (int ks = 0; ks < 4; ks++){
            c0 = __builtin_amdgcn_mfma_f32_16x16x32_bf16(ah[ks], wh[0][ks], c0, 0,0,0);
            c0 = __builtin_amdgcn_mfma_f32_16x16x32_bf16(ah[ks], wl[0][ks], c0, 0,0,0);
            c1 = __builtin_amdgcn_mfma_f32_16x16x32_bf16(ah[ks], wh[1][ks], c1, 0,0,0);
            c1 = __builtin_amdgcn_mfma_f32_16x16x32_bf16(ah[ks], wl[1][ks], c1, 0,0,0);
        }
        #pragma unroll
        for (int t = 0; t < 2; t++){
            f32x4 cc = t ? c1 : c0;
            int col = n0 + t*16 + lr;
            float bv = fcb[col];
            #pragma unroll
            for (int r = 0; r < 4; r++){
                int row = mt*16 + lk*4 + r;
                if (row < SEQL){
                    float v = fmaxf(cc[r] + bv, 0.f);
                    v += bs2f(st[col*104 + row]) + posl[(row+1)*128 + col];
                    tot[(size_t)b*SEQL*128 + (size_t)row*128 + col] = f2b(v);
                }
            }
        }
    }
}

// ================= MFMA GEMM =================
// C[row,128] = epilogue( A[M,128] @ W[n, wstride; +woff]^T ), row = outidx?outidx[m]:m
// W f32 -> bf16 hi+lo in-register. TA=bf16: 2 terms; TA=float: 3 terms.
// act: 0=none 1=relu 2=tanh 3=sigmoid
// addmode 1: += add1[((m%SEQL)+1)*masks[m]*128+n]; 2: += add1[(m/SEQL)*128+n]
// In-place safe via per-stripe __syncthreads.
template<typename TA, typename TC>
__global__ __launch_bounds__(256) void k_mgemm(const TA* __restrict__ A,
                                               const float* __restrict__ W, int wstride, int woff,
                                               const float* __restrict__ bias, int boff,
                                               TC* __restrict__ C, int act,
                                               const float* __restrict__ add1, int addmode,
                                               const int* __restrict__ masks,
                                               const int* __restrict__ outidx){
    constexpr bool A_BF = (sizeof(TA) == 2);
    int tid  = threadIdx.x;
    int wv   = tid >> 6;
    int lane = tid & 63;
    int lr   = lane & 15;
    int lk   = lane >> 4;
    int n0   = wv * 32;

    s16x8 wh[2][4], wl[2][4];
    #pragma unroll
    for (int t = 0; t < 2; t++){
        #pragma unroll
        for (int ks = 0; ks < 4; ks++){
            const float* wp = W + (size_t)(n0 + t*16 + lr)*wstride + woff + ks*32 + lk*8;
            float4 w0 = *(const float4*)(wp);
            float4 w1 = *(const float4*)(wp + 4);
            float wf[8] = {w0.x,w0.y,w0.z,w0.w,w1.x,w1.y,w1.z,w1.w};
            s16x8 h, l;
            #pragma unroll
            for (int j = 0; j < 8; j++){
                short hb = f2bs(wf[j]);
                h[j] = hb;
                l[j] = f2bs(wf[j] - bs2f(hb));
            }
            wh[t][ks] = h; wl[t][ks] = l;
        }
    }

    size_t mblk = (size_t)blockIdx.x * 128;
    for (int it = 0; it < 8; it++){
        size_t m0 = mblk + (size_t)it*16;
        s16x8 ah[4], al[4];
        #pragma unroll
        for (int ks = 0; ks < 4; ks++){
            if constexpr (A_BF){
                ah[ks] = *(const s16x8*)((const short*)A + (m0 + lr)*128 + ks*32 + lk*8);
            } else {
                const float* ap = (const float*)A + (m0 + lr)*128 + ks*32 + lk*8;
                float4 a0 = *(const float4*)(ap);
                float4 a1 = *(const float4*)(ap + 4);
                float av[8] = {a0.x,a0.y,a0.z,a0.w,a1.x,a1.y,a1.z,a1.w};
                s16x8 h, l;
                #pragma unroll
                for (int j = 0; j < 8; j++){
                    short hb = f2bs(av[j]);
                    h[j] = hb;
                    l[j] = f2bs(av[j] - bs2f(hb));
                }
                ah[ks] = h; al[ks] = l;
            }
        }
        __syncthreads();   // in-place safety: all reads of stripe before any writes
        f32x4 c0 = {0.f,0.f,0.f,0.f}, c1 = {0.f,0.f,0.f,0.f};
        #pragma unroll
        for (int ks = 0; ks < 4; ks++){
            c0 = __builtin_amdgcn_mfma_f32_16x16x32_bf16(ah[ks], wh[0][ks], c0, 0, 0, 0);
            c0 = __builtin_amdgcn_mfma_f32_16x16x32_bf16(ah[ks], wl[0][ks], c0, 0, 0, 0);
            c1 = __builtin_amdgcn_mfma_f32_16x16x32_bf16(ah[ks], wh[1][ks], c1, 0, 0, 0);
            c1 = __builtin_amdgcn_mfma_f32_16x16x32_bf16(ah[ks], wl[1][ks], c1, 0, 0, 0);
            if constexpr (!A_BF){
                c0 = __builtin_amdgcn_mfma_f32_16x16x32_bf16(al[ks], wh[0][ks], c0, 0, 0, 0);
                c1 = __builtin_amdgcn_mfma_f32_16x16x32_bf16(al[ks], wh[1][ks], c1, 0, 0, 0);
            }
        }
        #pragma unroll
        for (int t = 0; t < 2; t++){
            f32x4 cc = t ? c1 : c0;
            int c = n0 + t*16 + lr;
            float bv = bias ? bias[boff + c] : 0.f;
            #pragma unroll
            for (int r4 = 0; r4 < 4; r4++){
                int m = (int)m0 + lk*4 + r4;
                float v = cc[r4] + bv;
                if (addmode == 1){
                    int l = m % SEQL;
                    int p = (l+1) * masks[m];
                    v += add1[p*128 + c];
                } else if (addmode == 2){
                    v += add1[(m/SEQL)*128 + c];
                }
                if (act == 1) v = fmaxf(v, 0.f);
                else if (act == 2) v = tanhf(v);
                else if (act == 3) v = 1.f/(1.f+__expf(-v));
                size_t orow = outidx ? (size_t)outidx[m] : (size_t)m;
                stc(&C[orow*128 + c], v);
            }
        }
    }
}

// ================= MFMA attention + fused column-mean =================
// One block per b; 4 waves x 2 heads. d_head=16 -> K=32 MFMA with upper half zero.
// O is NEVER stored: only mean_l(O[b]) is needed downstream (out-proj is linear),
// so the epilogue accumulates per-column f32 means -> Omean[b,128].
__global__ __launch_bounds__(256) void k_mattn(float* __restrict__ Omean,
                                               const bf16* __restrict__ Qq,
                                               const bf16* __restrict__ Qk,
                                               const bf16* __restrict__ Qv){
    __shared__ short Vt[128*104];      // V^T, pitch 104
    __shared__ short Ph[4][16*136];    // per-wave P stripe (hi), pitch 136
    __shared__ short Pl[4][16*136];    // per-wave P stripe (lo)
    int b = blockIdx.x, tid = threadIdx.x;
    const short* vsrc = (const short*)(Qv + (size_t)b*SEQL*128);
    for (int i = tid; i < SEQL*128; i += 256){ int j = i>>7, c = i&127; Vt[c*104 + j] = vsrc[i]; }
    for (int i = tid; i < 128*4; i += 256){ int c = i>>2, r = i&3; Vt[c*104 + 100 + r] = 0; }
    int wv = tid>>6, lane = tid&63, lr = lane&15, lk = lane>>4;
    short* phw = Ph[wv];
    short* plw = Pl[wv];
    for (int i = lane; i < 16*136; i += 64){ phw[i] = 0; plw[i] = 0; }
    __syncthreads();

    const s16x8 zf = {0,0,0,0,0,0,0,0};
    size_t rowbase = (size_t)b*SEQL*128;
    bool kreal = (lk < 2);
    for (int hh = 0; hh < 2; hh++){
        int h = wv*2 + hh;
        int hd = h*16 + lk*8;
        s16x8 kf[7];
        #pragma unroll
        for (int nt = 0; nt < 7; nt++){
            int kr = min(nt*16 + lr, SEQL-1);
            kf[nt] = kreal ? *(const s16x8*)((const short*)Qk + rowbase + (size_t)kr*128 + hd) : zf;
        }
        s16x8 vf[4];
        #pragma unroll
        for (int kc = 0; kc < 4; kc++)
            vf[kc] = *(const s16x8*)&Vt[(h*16+lr)*104 + kc*32 + lk*8];

        float msum = 0.f;     // partial column-mean accumulator (col = h*16+lr)
        for (int mt = 0; mt < 7; mt++){
            int qr = min(mt*16 + lr, SEQL-1);
            s16x8 qf = kreal ? *(const s16x8*)((const short*)Qq + rowbase + (size_t)qr*128 + hd) : zf;
            f32x4 sc[7];
            #pragma unroll
            for (int nt = 0; nt < 7; nt++){
                f32x4 z = {0.f,0.f,0.f,0.f};
                sc[nt] = __builtin_amdgcn_mfma_f32_16x16x32_bf16(qf, kf[nt], z, 0,0,0);
            }
            float mx[4] = {-1e30f,-1e30f,-1e30f,-1e30f};
            #pragma unroll
            for (int nt = 0; nt < 7; nt++){
                bool masked = (nt == 6) && (lr >= 4);   // cols >= 100
                #pragma unroll
                for (int r = 0; r < 4; r++){
                    float s = masked ? -1e30f : sc[nt][r]*0.25f;
                    sc[nt][r] = s;
                    mx[r] = fmaxf(mx[r], s);
                }
            }
            #pragma unroll
            for (int m = 1; m < 16; m <<= 1){
                #pragma unroll
                for (int r = 0; r < 4; r++) mx[r] = fmaxf(mx[r], __shfl_xor(mx[r], m));
            }
            float sm[4] = {0.f,0.f,0.f,0.f};
            #pragma unroll
            for (int nt = 0; nt < 7; nt++){
                #pragma unroll
                for (int r = 0; r < 4; r++){
                    float p = __expf(sc[nt][r] - mx[r]);
                    sc[nt][r] = p; sm[r] += p;
                }
            }
            #pragma unroll
            for (int m = 1; m < 16; m <<= 1){
                #pragma unroll
                for (int r = 0; r < 4; r++) sm[r] += __shfl_xor(sm[r], m);
            }
            float inv[4];
            #pragma unroll
            for (int r = 0; r < 4; r++) inv[r] = 1.f/sm[r];
            #pragma unroll
            for (int nt = 0; nt < 7; nt++){
                #pragma unroll
                for (int r = 0; r < 4; r++){
                    float p = sc[nt][r]*inv[r];
                    short hb = f2bs(p);
                    int pa = (lk*4+r)*136 + nt*16 + lr;
                    phw[pa] = hb;
                    plw[pa] = f2bs(p - bs2f(hb));
                }
            }
            f32x4 oa = {0.f,0.f,0.f,0.f};
            #pragma unroll
            for (int kc = 0; kc < 4; kc++){
                s16x8 pah = *(const s16x8*)&phw[lr*136 + kc*32 + lk*8];
                s16x8 pal = *(const s16x8*)&plw[lr*136 + kc*32 + lk*8];
                oa = __builtin_amdgcn_mfma_f32_16x16x32_bf16(pah, vf[kc], oa, 0,0,0);
                oa = __builtin_amdgcn_mfma_f32_16x16x32_bf16(pal, vf[kc], oa, 0,0,0);
            }
            #pragma unroll
            for (int r = 0; r < 4; r++){
                int row = mt*16 + lk*4 + r;
                if (row < SEQL) msum += oa[r];
            }
        }
        // reduce over lk (lanes sharing col = h*16+lr), write mean
        msum += __shfl_xor(msum, 16);
        msum += __shfl_xor(msum, 32);
        if (lk == 0) Omean[(size_t)b*128 + h*16 + lr] = msum * (1.f/(float)SEQL);
    }
}

// ================= CSR build + row-wave SpMM =================

__global__ __launch_bounds__(256) void k_hist(int* __restrict__ cnt,
                                              const int* __restrict__ rows, int nnz){
    int e = blockIdx.x*256 + threadIdx.x;
    if (e < nnz) atomicAdd(&cnt[rows[e]], 1);
}

__global__ __launch_bounds__(1024) void k_scan(int* __restrict__ cnt,
                                               int* __restrict__ rowptr, int nrows){
    __shared__ int part[1024];
    int tid = threadIdx.x;
    int chunk = (nrows + 1023) >> 10;
    int s = tid*chunk, e = min(s+chunk, nrows);
    int sum = 0;
    for (int i = s; i < e; i++) sum += cnt[i];
    part[tid] = sum;
    __syncthreads();
    for (int off = 1; off < 1024; off <<= 1){
        int add = (tid >= off) ? part[tid-off] : 0;
        __syncthreads();
        part[tid] += add;
        __syncthreads();
    }
    int run = part[tid] - sum;
    for (int i = s; i < e; i++){
        int c = cnt[i];
        rowptr[i] = run;
        cnt[i]    = run;
        run += c;
    }
    if (tid == 0) rowptr[nrows] = part[1023];
}

__global__ __launch_bounds__(256) void k_scatter(int2* __restrict__ cv,
                                                 int* __restrict__ cur,
                                                 const int* __restrict__ rows,
                                                 const int* __restrict__ cols,
                                                 const float* __restrict__ vals, int nnz){
    int e = blockIdx.x*256 + threadIdx.x;
    if (e >= nnz) return;
    int p = atomicAdd(&cur[rows[e]], 1);
    cv[p] = make_int2(cols[e], __float_as_int(vals[e]));
}

// one wave per row, 8 edge-slots x 8 lanes; lane loads 32B (16 bf16) of x-row.
// Writes result row to yb (bf16) and acc += (single writer per row).
// x must be a SNAPSHOT distinct from yb.
__global__ __launch_bounds__(256) void k_spmm_csr(bf16* __restrict__ yb,
                                                  float* __restrict__ acc,
                                                  const int* __restrict__ rowptr,
                                                  const int2* __restrict__ cv,
                                                  const bf16* __restrict__ x, int nrows){
    int row = blockIdx.x*4 + (threadIdx.x >> 6);
    if (row >= nrows) return;
    int lane = threadIdx.x & 63;
    int g = lane >> 3;           // edge-slot 0..7
    int t = lane & 7;            // col-group: cols t*16 .. t*16+15
    int s = rowptr[row], e = rowptr[row+1];
    float a[16];
    #pragma unroll
    for (int j = 0; j < 16; j++) a[j] = 0.f;
    for (int i = s + g; i < e; i += 8){
        int2 p = cv[i];
        float v = __int_as_float(p.y);
        const unsigned* xp = (const unsigned*)(x + (size_t)p.x*128 + t*16);
        uint4 u0 = *(const uint4*)xp;
        uint4 u1 = *(const uint4*)(xp + 4);
        unsigned w[8] = {u0.x,u0.y,u0.z,u0.w,u1.x,u1.y,u1.z,u1.w};
        #pragma unroll
        for (int j = 0; j < 8; j++){
            a[2*j]   += v * __uint_as_float((w[j] & 0xffffu) << 16);
            a[2*j+1] += v * __uint_as_float(w[j] & 0xffff0000u);
        }
    }
    #pragma unroll
    for (int j = 0; j < 16; j++){
        a[j] += __shfl_xor(a[j], 8);
        a[j] += __shfl_xor(a[j], 16);
        a[j] += __shfl_xor(a[j], 32);
    }
    if (g == 0){
        s16x8 o0, o1;
        #pragma unroll
        for (int j = 0; j < 8; j++){ o0[j] = f2bs(a[j]); o1[j] = f2bs(a[8+j]); }
        short* yp = (short*)yb + (size_t)row*128 + t*16;
        *(s16x8*)yp = o0;
        *(s16x8*)(yp + 8) = o1;
        float* ap = acc + (size_t)row*128 + t*16;
        #pragma unroll
        for (int q = 0; q < 4; q++){
            float4 c = ((float4*)ap)[q];
            c.x += a[q*4+0]; c.y += a[q*4+1]; c.z += a[q*4+2]; c.w += a[q*4+3];
            ((float4*)ap)[q] = c;
        }
    }
}

__global__ __launch_bounds__(256) void k_scale(float* __restrict__ a, int n){
    int i = blockIdx.x*256 + threadIdx.x;
    if (i < n) a[i] *= (1.f/3.f);
}

// ---------- global branch init ----------
__global__ __launch_bounds__(256) void k_initg(bf16* __restrict__ xg, float* __restrict__ accg,
                                               const float* __restrict__ ne, int n){
    int i = blockIdx.x*256 + threadIdx.x;
    if (i >= n) return;
    float v = ne[(size_t)NUSERS*128 + i];
    xg[i] = f2b(v); accg[i] = v;
}

// ---------- fusion: acc_poi += accg/3; emit pois output (f32!) ----------
__global__ __launch_bounds__(256) void k_fusion(float* __restrict__ accP,
                                                const float* __restrict__ accg,
                                                float* __restrict__ outp, int n){
    int i = blockIdx.x*256 + threadIdx.x;
    if (i >= n) return;
    float v = accP[i] + accg[i]*(1.f/3.f);
    accP[i] = v;
    outp[i] = v;
}

// ================= HEAD =================

__global__ __launch_bounds__(128) void k_hs(float* __restrict__ hs, const float* __restrict__ sh,
                                            const float* __restrict__ lens){
    int b = blockIdx.x, c = threadIdx.x;
    const float* p = sh + (size_t)b*SEQL*128 + c;
    float sum = 0.f;
    for (int l = 0; l < SEQL; l++) sum += p[l*128];
    hs[b*128 + c] = sum / lens[b];
}

__global__ __launch_bounds__(128) void k_posw(float* __restrict__ posW,
                                              const float* __restrict__ pg,
                                              const float* __restrict__ w1w){
    __shared__ float sm[128];
    int p = blockIdx.x, n = threadIdx.x;
    sm[n] = pg[p*128 + n];
    __syncthreads();
    const float* wr = w1w + (size_t)n*256;
    float s = 0.f;
    for (int k = 0; k < 128; k++) s += sm[k]*wr[k];
    posW[p*128 + n] = s;
}

// ---------- beta: per-wave reduction, 4 rows/block ----------
__global__ __launch_bounds__(256) void k_beta(float* __restrict__ beta,
                                              const bf16* __restrict__ nh,
                                              const float* __restrict__ w2){
    int m = blockIdx.x*4 + (threadIdx.x >> 6);
    int lane = threadIdx.x & 63;
    float v = b2f(nh[(size_t)m*128 + lane]) * w2[lane]
            + b2f(nh[(size_t)m*128 + 64 + lane]) * w2[64 + lane];
    #pragma unroll
    for (int s = 1; s < 64; s <<= 1) v += __shfl_xor(v, s);
    if (lane == 0) beta[m] = v;
}

__global__ __launch_bounds__(128) void k_final(float* __restrict__ out,
                                               const float* __restrict__ beta,
                                               const float* __restrict__ seqh,
                                               const float* __restrict__ acc,
                                               const int* __restrict__ uidx){
    int b = blockIdx.x, c = threadIdx.x;
    const float* sh = seqh + (size_t)b*SEQL*128 + c;
    const float* bp = beta + b*SEQL;
    float sel = 0.f;
    for (int l = 0; l < SEQL; l++) sel += bp[l]*sh[l*128];
    out[b*128 + c] = sel + acc[(size_t)uidx[b]*128 + c];
}

extern "C" void kernel_launch(void* const* d_in, const int* in_sizes, int n_in,
                              void* d_out, int out_size, void* d_ws, size_t ws_size,
                              hipStream_t stream){
    const float* nodes_emb     = (const float*)d_in[0];
    const float* pos_emb_local = (const float*)d_in[1];
    const float* fc_geo_w      = (const float*)d_in[2];
    const float* fc_geo_b      = (const float*)d_in[3];
    const float* in_proj_w     = (const float*)d_in[4];
    const float* in_proj_b     = (const float*)d_in[5];
    const float* out_proj_w    = (const float*)d_in[6];
    const float* out_proj_b    = (const float*)d_in[7];
    const float* pos_emb_glob  = (const float*)d_in[8];
    const float* w1_w          = (const float*)d_in[9];
    const float* w1_b          = (const float*)d_in[10];
    const float* w_2           = (const float*)d_in[11];
    const float* glu1_w        = (const float*)d_in[12];
    const float* glu1_b        = (const float*)d_in[13];
    const float* glu2_w        = (const float*)d_in[14];
    const int*   G_rows        = (const int*)d_in[15];
    const int*   G_cols        = (const int*)d_in[16];
    const float* G_vals        = (const float*)d_in[17];
    const int*   HG_rows       = (const int*)d_in[18];
    const int*   HG_cols       = (const int*)d_in[19];
    const float* HG_vals       = (const float*)d_in[20];
    const int*   seqs          = (const int*)d_in[21];
    const int*   masks         = (const int*)d_in[22];
    const float* adjs          = (const float*)d_in[23];
    const int*   uidx          = (const int*)d_in[24];
    const float* lens          = (const float*)d_in[25];
    const int*   rev_seqs      = (const int*)d_in[26];
    float* out = (float*)d_out;   // OUTPUT IS FLOAT32

    // ---- workspace layout; max offset used = 124,723,968 B ----
    char* base = (char*)d_ws;
    bf16*  nodes = (bf16*)base;                               // [0, 15,360,256)
    float* acc   = (float*)(base + 15360256);                 // [.., 46,080,768)
    char*  R     = base + 15360256 + 30720512;                // [46,080,768, 124,723,968)
    // layer-phase aliases inside R:
    bf16* P1 = (bf16*)R;          // BLD bf16
    bf16* P2 = P1 + BLD;
    bf16* P3 = P2 + BLD;
    // spmm-window alias (P1 dead):
    bf16*  xsnap = (bf16*)R;                         // 60000-row bf16 snapshot (15.36 MB)
    // global-phase aliases:
    bf16*  xg     = (bf16*)R;                        // PD bf16
    bf16*  xsnapg = (bf16*)(R + 12800000);           // PD bf16 snapshot
    float* accg = (float*)(R + 12800000 + 25600000); // PD f32 -> ends 64,000,000
    int2*  Hcv  = (int2*)(R + 64000000);             // NNZH*8 -> ends 76,800,000
    int*   Hptr = (int*)(R + 76800000);              // 50001*4
    int*   Hcur = (int*)(R + 77000016);              // 50000*4 (16B aligned)
    // head-phase aliases:
    float* H1f  = (float*)R;                         // BLD f32
    bf16*  nh   = (bf16*)(R + 52428800);             // BLD bf16 -> ends 78,643,200
    float* hs    = (float*)base;                     // small bufs in dead nodes region
    float* hproj = (float*)(base + 524288);
    float* posW  = (float*)(base + 1048576);
    float* betaB = (float*)(base + 1100288);
    // G-CSR + Omean scratch lives in the OUT buffer (dead until k_fusion/k_final,
    // which only write at the very end): total 16.4 MB < 26.1 MB out size.
    char*  ob    = (char*)out;
    int2*  Gcv   = (int2*)ob;                        // 15,360,000
    int*   Gptr  = (int*)(ob + 15360000);            // 240,004
    int*   Gcur  = (int*)(ob + 15600016);            // 240,000 (16B aligned)
    float* Omean = (float*)(ob + 15840016);          // 524,288 -> ends 16,364,304

    auto gemm = [&](const bf16* A, const float* W, int wstride, int woff,
                    const float* bias, int boff, bf16* Cp, int act){
        k_mgemm<bf16,bf16><<<dim3(BL/128), dim3(256), 0, stream>>>(
            A, W, wstride, woff, bias, boff, Cp, act, nullptr, 0, nullptr, nullptr);
    };

    // init: nodes (bf16) = nodes_emb, acc (f32) = nodes_emb
    k_init<<<dim3((NND+255)/256), dim3(256), 0, stream>>>(nodes, acc, nodes_emb, NND);

    // ---- build G CSR ONCE (input graph is constant; scratch in out buffer) ----
    k_zero<<<dim3((15000+255)/256), dim3(256), 0, stream>>>((float*)Gcur, 15000); // 60000 ints
    k_hist<<<dim3(NNZG/256), dim3(256), 0, stream>>>(Gcur, G_rows, NNZG);
    k_scan<<<dim3(1), dim3(1024), 0, stream>>>(Gcur, Gptr, 60000);
    k_scatter<<<dim3(NNZG/256), dim3(256), 0, stream>>>(Gcv, Gcur, G_rows, G_cols, G_vals, NNZG);

    for (int layer = 0; layer < 2; layer++){
        // fused gather + geo + fc_geo + tot -> P3
        k_mgeo2<<<dim3(BATCH), dim3(256), 0, stream>>>(P3, nodes, seqs, adjs,
                                                       fc_geo_w, fc_geo_b, pos_emb_local);
        gemm(P3, in_proj_w, 128, 0,       in_proj_b, 0,   P1, 0); // Q
        gemm(P3, in_proj_w, 128, 128*128, in_proj_b, 128, P2, 0); // K
        gemm(P3, in_proj_w, 128, 256*128, in_proj_b, 256, P3, 0); // V in-place
        // attention with fused column-mean (O never materialized)
        k_mattn<<<dim3(BATCH), dim3(256), 0, stream>>>(Omean, P1, P2, P3);
        // users = Omean @ outW^T + outB, scattered into nodes[uidx] (1024-row GEMM)
        k_mgemm<float,bf16><<<dim3(BATCH/128), dim3(256), 0, stream>>>(
            Omean, out_proj_w, 128, 0, out_proj_b, 0, nodes, 0, nullptr, 0, nullptr, uidx);
        // snapshot x, then SpMM writes nodes (bf16) + acc += directly
        k_copy16<<<dim3((960000+255)/256), dim3(256), 0, stream>>>(
            (ulong2*)xsnap, (const ulong2*)nodes, 960000);
        k_spmm_csr<<<dim3(60000/4), dim3(256), 0, stream>>>(nodes, acc, Gptr, Gcv, xsnap, 60000);
    }
    // local = acc/3
    k_scale<<<dim3((NND+255)/256), dim3(256), 0, stream>>>(acc, NND);

    // global hypergraph branch
    k_initg<<<dim3((PD+255)/256), dim3(256), 0, stream>>>(xg, accg, nodes_emb, PD);
    k_zero<<<dim3((12500+255)/256), dim3(256), 0, stream>>>((float*)Hcur, 12500); // 50000 ints
    k_hist<<<dim3(NNZH/256), dim3(256), 0, stream>>>(Hcur, HG_rows, NNZH);
    k_scan<<<dim3(1), dim3(1024), 0, stream>>>(Hcur, Hptr, 50000);
    k_scatter<<<dim3(NNZH/256), dim3(256), 0, stream>>>(Hcv, Hcur, HG_rows, HG_cols, HG_vals, NNZH);
    for (int it = 0; it < 2; it++){
        k_copy16<<<dim3((800000+255)/256), dim3(256), 0, stream>>>(
            (ulong2*)xsnapg, (const ulong2*)xg, 800000);
        k_spmm_csr<<<dim3(50000/4), dim3(256), 0, stream>>>(xg, accg, Hptr, Hcv, xsnapg, 50000);
    }
    // fusion: pois rows of acc += accg/3, emit pois output (f32, offset in f32 elems)
    // (this overwrites the Gcv scratch region of out — Gcv is dead by now)
    k_fusion<<<dim3((PD+255)/256), dim3(256), 0, stream>>>(acc + (size_t)NUSERS*128, accg, out + BATCH*128, PD);

    // ===== head (f32 path) =====
    k_gather_f<<<dim3((BL*128+255)/256), dim3(256), 0, stream>>>(H1f, acc, rev_seqs, BL);
    k_hs<<<dim3(BATCH), dim3(128), 0, stream>>>(hs, H1f, lens);
    // hproj = hs @ glu2_w^T  (f32-A 3-term MFMA path)
    k_mgemm<float,float><<<dim3(BATCH/128), dim3(256), 0, stream>>>(
        hs, glu2_w, 128, 0, nullptr, 0, hproj, 0, nullptr, 0, nullptr, nullptr);
    k_posw<<<dim3(SEQL+1), dim3(128), 0, stream>>>(posW, pos_emb_glob, w1_w);
    // nh1 = tanh(H1f @ w1_w[:,128:]^T + posW[pidx] + w1_b)
    k_mgemm<float,bf16><<<dim3(BL/128), dim3(256), 0, stream>>>(
        H1f, w1_w, 256, 128, w1_b, 0, nh, 2, posW, 1, masks, nullptr);
    // nh2 = sigmoid(nh @ glu1_w^T + glu1_b + hproj[b])  (in-place, barrier-protected)
    k_mgemm<bf16,bf16><<<dim3(BL/128), dim3(256), 0, stream>>>(
        nh, glu1_w, 128, 0, glu1_b, 0, nh, 3, hproj, 2, nullptr, nullptr);
    k_beta<<<dim3(BL/4), dim3(256), 0, stream>>>(betaB, nh, w_2);
    k_final<<<dim3(BATCH), dim3(128), 0, stream>>>(out, betaB, H1f, acc, uidx);
}